// Round 1
// baseline (410.792 us; speedup 1.0000x reference)
//
#include <hip/hip_runtime.h>

#define B_    8
#define T_    512
#define D_    768
#define L_    16
#define DL_   128
#define NO_   4096   // L_*DL_*2
#define M_    4096   // B_*T_
#define BN_EPS 1e-5f

typedef __attribute__((ext_vector_type(8))) short short8;
typedef __attribute__((ext_vector_type(4))) float f32x4;

__device__ inline unsigned short f2bf(float x) {
    unsigned int u = __float_as_uint(x);
    unsigned int r = (u + 0x7fffu + ((u >> 16) & 1u)) >> 16;
    return (unsigned short)r;
}

// async global -> LDS, 16 bytes per lane (dest = uniform base + lane*16)
__device__ __forceinline__ void gload_lds16(const unsigned short* g, unsigned short* l) {
    __builtin_amdgcn_global_load_lds(
        (const __attribute__((address_space(1))) unsigned int*)g,
        (__attribute__((address_space(3))) unsigned int*)l, 16, 0, 0);
}

// ---------------- Kernel 1: masked per-channel sum / sumsq / count ----------
// grid 256 x 256. stats layout (floats): [0..767]=sum, [768..1535]=sumsq,
// [1536]=cnt, [2048..2815]=scale, [2816..3583]=shift
__global__ void k_stats(const float* __restrict__ f, const int* __restrict__ mask,
                        float* __restrict__ stats) {
    int tid = threadIdx.x;
    int t0  = blockIdx.x * 16;
    float s0 = 0.f, s1 = 0.f, s2 = 0.f, q0 = 0.f, q1 = 0.f, q2 = 0.f;
    for (int tt = 0; tt < 16; ++tt) {
        int t = t0 + tt;
        float m = mask[t] ? 1.f : 0.f;
        const float* row = f + (size_t)t * D_;
        float x0 = row[tid];
        float x1 = row[tid + 256];
        float x2 = row[tid + 512];
        s0 += x0 * m; q0 += x0 * x0 * m;
        s1 += x1 * m; q1 += x1 * x1 * m;
        s2 += x2 * m; q2 += x2 * x2 * m;
    }
    atomicAdd(&stats[tid      ], s0);
    atomicAdd(&stats[tid + 256], s1);
    atomicAdd(&stats[tid + 512], s2);
    atomicAdd(&stats[768 + tid      ], q0);
    atomicAdd(&stats[768 + tid + 256], q1);
    atomicAdd(&stats[768 + tid + 512], q2);
    if (tid == 0) {
        int c = 0;
        for (int tt = 0; tt < 16; ++tt) c += (mask[t0 + tt] ? 1 : 0);
        atomicAdd(&stats[1536], (float)c);
    }
}

// ---------------- Kernel 1b: finalize scale/shift ---------------------------
__global__ void k_finalize(const float* __restrict__ gamma, const float* __restrict__ beta,
                           float* __restrict__ stats) {
    int d = threadIdx.x;  // 768
    float denom = fmaxf(stats[1536], 1.f);
    float mean  = stats[d] / denom;
    float var   = fmaxf(stats[768 + d] / denom - mean * mean, 0.f);
    float sc    = gamma[d] * rsqrtf(var + BN_EPS);
    stats[2048 + d] = sc;
    stats[2816 + d] = beta[d] - mean * sc;
}

// ---------------- Kernel 2: normalize+mask+cast feats, cast ff_w ------------
// grid 6144 x 256. First 3072 blocks: norm path over M_*D_/4 float4.
// Last 3072 blocks: cast ff_w (NO_*D_/4 float4).
__global__ void k_normcast(const float4* __restrict__ f4, const float4* __restrict__ w4,
                           const int* __restrict__ mask, const float* __restrict__ stats,
                           unsigned short* __restrict__ featp, unsigned short* __restrict__ wp) {
    int i = blockIdx.x * 256 + threadIdx.x;
    if (i < M_ * D_ / 4) {
        int d4 = i % (D_ / 4);
        int t  = i / (D_ / 4);
        float m = mask[t] ? 1.f : 0.f;
        float4 v = f4[i];
        int d = d4 * 4;
        float r0 = (v.x * stats[2048 + d + 0] + stats[2816 + d + 0]) * m;
        float r1 = (v.y * stats[2048 + d + 1] + stats[2816 + d + 1]) * m;
        float r2 = (v.z * stats[2048 + d + 2] + stats[2816 + d + 2]) * m;
        float r3 = (v.w * stats[2048 + d + 3] + stats[2816 + d + 3]) * m;
        ushort4 o;
        o.x = f2bf(r0); o.y = f2bf(r1); o.z = f2bf(r2); o.w = f2bf(r3);
        ((ushort4*)featp)[i] = o;
    } else {
        int j = i - M_ * D_ / 4;
        float4 v = w4[j];
        ushort4 o;
        o.x = f2bf(v.x); o.y = f2bf(v.y); o.z = f2bf(v.z); o.w = f2bf(v.w);
        ((ushort4*)wp)[j] = o;
    }
}

// ---------------- Kernel 3: FFN GEMM (h = relu(feats @ W^T + b)) ------------
// m97 structure: 128x128 tile, BK=32, linear LDS [128][32], global_load_lds
// width 16, 2 barriers per K-step. Epilogue scatters into start/end arrays
// with layout [B][L][T][DL] bf16 each.
__launch_bounds__(256)
__global__ void k_ffn(const unsigned short* __restrict__ A, const unsigned short* __restrict__ W,
                      const float* __restrict__ bias,
                      unsigned short* __restrict__ startp, unsigned short* __restrict__ endp) {
    __shared__ alignas(16) unsigned short As[128 * 32];
    __shared__ alignas(16) unsigned short Bs[128 * 32];
    int tid  = threadIdx.x;
    int bm   = blockIdx.x, bn = blockIdx.y;
    int wave = tid >> 6, lane = tid & 63;
    int wm = wave >> 1, wn = wave & 1;
    int lr = lane & 15, quad = lane >> 4;
    f32x4 acc[4][4] = {};
    const int K = D_;
    // staging geometry: tile = 128 rows x 32 cols bf16 = 8 KiB = 8 chunks x 1 KiB.
    // wave w stages chunks {2w, 2w+1} of A and of B. lane l covers
    // lds offset c*1024 + l*16  <=>  row = c*16 + l/4, colshort = (l&3)*8.
    int srow   = (lane >> 2);
    int scolsh = (lane & 3) * 8;
    for (int k0 = 0; k0 < K; k0 += 32) {
#pragma unroll
        for (int p = 0; p < 2; ++p) {
            int c   = wave * 2 + p;
            int row = c * 16 + srow;
            gload_lds16(A + (size_t)(bm * 128 + row) * K + k0 + scolsh, &As[c * 512]);
            gload_lds16(W + (size_t)(bn * 128 + row) * K + k0 + scolsh, &Bs[c * 512]);
        }
        __syncthreads();
        short8 a[4], b[4];
#pragma unroll
        for (int i = 0; i < 4; ++i) a[i] = *(const short8*)&As[(wm * 64 + i * 16 + lr) * 32 + quad * 8];
#pragma unroll
        for (int i = 0; i < 4; ++i) b[i] = *(const short8*)&Bs[(wn * 64 + i * 16 + lr) * 32 + quad * 8];
#pragma unroll
        for (int i = 0; i < 4; ++i)
#pragma unroll
            for (int j = 0; j < 4; ++j)
                acc[i][j] = __builtin_amdgcn_mfma_f32_16x16x32_bf16(a[i], b[j], acc[i][j], 0, 0, 0);
        __syncthreads();
    }
#pragma unroll
    for (int i = 0; i < 4; ++i) {
#pragma unroll
        for (int j = 0; j < 4; ++j) {
            int col  = bn * 128 + wn * 64 + j * 16 + lr;   // output channel o
            int l    = col >> 8;
            int dd   = (col >> 1) & 127;
            int cbit = col & 1;
            unsigned short* dst = cbit ? endp : startp;
            float bv = bias[col];
#pragma unroll
            for (int r = 0; r < 4; ++r) {
                int row = bm * 128 + wm * 64 + i * 16 + quad * 4 + r;  // token
                float v = acc[i][j][r] + bv;
                v = fmaxf(v, 0.f);
                int bb = row >> 9, tt = row & 511;
                dst[(((size_t)(bb * 16 + l) * 512 + tt) << 7) + dd] = f2bf(v);
            }
        }
    }
}

// ---------------- Kernel 4: biaffine scores + spans_mask (fused) ------------
// per (b,l): C[s,e] = sum_d start[s,d]*end[e,d] + label_bias[l]
// K=128 is tiny and the per-(b,l) working set (256 KiB) is L2-resident:
// no LDS, no barriers — MFMA fragments loaded straight from global.
// Also writes spans_mask for the same (b,l,s,e) tile (replaces k_mask).
// grid (4,4,128), block 256
__launch_bounds__(256)
__global__ void k_biaffine(const unsigned short* __restrict__ startp,
                           const unsigned short* __restrict__ endp,
                           const int* __restrict__ mask,
                           const float* __restrict__ lbias,
                           float* __restrict__ out_scores, float* __restrict__ out_mask) {
    int tid = threadIdx.x;
    int bm = blockIdx.x, bn = blockIdx.y;
    int bl = blockIdx.z;  // b*16 + l
    int b  = bl >> 4;
    const unsigned short* A  = startp + (size_t)bl * 512 * 128;
    const unsigned short* Bp = endp   + (size_t)bl * 512 * 128;
    int wave = tid >> 6, lane = tid & 63;
    int wm = wave >> 1, wn = wave & 1;
    int lr = lane & 15, quad = lane >> 4;
    f32x4 acc[4][4] = {};
#pragma unroll
    for (int k0 = 0; k0 < DL_; k0 += 32) {
        short8 a[4], bb[4];
#pragma unroll
        for (int i = 0; i < 4; ++i)
            a[i] = *(const short8*)(A + (size_t)(bm * 128 + wm * 64 + i * 16 + lr) * DL_ + k0 + quad * 8);
#pragma unroll
        for (int j = 0; j < 4; ++j)
            bb[j] = *(const short8*)(Bp + (size_t)(bn * 128 + wn * 64 + j * 16 + lr) * DL_ + k0 + quad * 8);
#pragma unroll
        for (int i = 0; i < 4; ++i)
#pragma unroll
            for (int j = 0; j < 4; ++j)
                acc[i][j] = __builtin_amdgcn_mfma_f32_16x16x32_bf16(a[i], bb[j], acc[i][j], 0, 0, 0);
    }
    float lb = lbias[bl & 15];
    float* obase = out_scores + (size_t)bl * 512 * 512;
    float* mbase = out_mask   + (size_t)bl * 512 * 512;
    // start-token mask values for the 16 rows this lane owns
    float msv[4][4];
#pragma unroll
    for (int i = 0; i < 4; ++i)
#pragma unroll
        for (int r = 0; r < 4; ++r) {
            int s = bm * 128 + wm * 64 + i * 16 + quad * 4 + r;
            msv[i][r] = mask[b * 512 + s] ? 1.f : 0.f;
        }
#pragma unroll
    for (int j = 0; j < 4; ++j) {
        int e = bn * 128 + wn * 64 + j * 16 + lr;
        float me = mask[b * 512 + e] ? 1.f : 0.f;
#pragma unroll
        for (int i = 0; i < 4; ++i) {
#pragma unroll
            for (int r = 0; r < 4; ++r) {
                int s = bm * 128 + wm * 64 + i * 16 + quad * 4 + r;
                size_t off = (size_t)s * 512 + e;
                obase[off] = acc[i][j][r] + lb;
                mbase[off] = (s <= e) ? msv[i][r] * me : 0.f;
            }
        }
    }
}

extern "C" void kernel_launch(void* const* d_in, const int* in_sizes, int n_in,
                              void* d_out, int out_size, void* d_ws, size_t ws_size,
                              hipStream_t stream) {
    const float* features = (const float*)d_in[0];
    const int*   mask     = (const int*)d_in[1];
    const float* gamma    = (const float*)d_in[2];
    const float* beta     = (const float*)d_in[3];
    const float* ffw      = (const float*)d_in[4];
    const float* ffb      = (const float*)d_in[5];
    const float* lbias    = (const float*)d_in[6];

    float* out_scores = (float*)d_out;
    float* out_mask   = out_scores + (size_t)B_ * L_ * T_ * T_;  // 33554432

    char* ws = (char*)d_ws;
    float*          stats  = (float*)ws;                              // 16 KiB
    unsigned short* feats  = (unsigned short*)(ws + 16384);           // 6 MiB
    unsigned short* wbf    = (unsigned short*)(ws + 16384 + 6291456); // 6 MiB
    unsigned short* startp = (unsigned short*)(ws + 12599296);        // 16 MiB
    unsigned short* endp   = (unsigned short*)(ws + 29376512);        // 16 MiB

    hipMemsetAsync(ws, 0, 16384, stream);
    k_stats<<<256, 256, 0, stream>>>(features, mask, stats);
    k_finalize<<<1, 768, 0, stream>>>(gamma, beta, stats);
    k_normcast<<<6144, 256, 0, stream>>>((const float4*)features, (const float4*)ffw,
                                         mask, stats, feats, wbf);
    dim3 g1(32, 32);
    k_ffn<<<g1, 256, 0, stream>>>(feats, wbf, ffb, startp, endp);
    dim3 g2(4, 4, 128);
    k_biaffine<<<g2, 256, 0, stream>>>(startp, endp, mask, lbias, out_scores, out_mask);
}

// Round 2
// 408.356 us; speedup vs baseline: 1.0060x; 1.0060x over previous
//
#include <hip/hip_runtime.h>

#define B_    8
#define T_    512
#define D_    768
#define L_    16
#define DL_   128
#define NO_   4096   // L_*DL_*2
#define M_    4096   // B_*T_
#define BN_EPS 1e-5f

typedef __attribute__((ext_vector_type(8))) short short8;
typedef __attribute__((ext_vector_type(4))) float f32x4;

__device__ inline unsigned short f2bf(float x) {
    unsigned int u = __float_as_uint(x);
    unsigned int r = (u + 0x7fffu + ((u >> 16) & 1u)) >> 16;
    return (unsigned short)r;
}

// async global -> LDS, 16 bytes per lane (dest = uniform base + lane*16)
__device__ __forceinline__ void gload_lds16(const unsigned short* g, unsigned short* l) {
    __builtin_amdgcn_global_load_lds(
        (const __attribute__((address_space(1))) unsigned int*)g,
        (__attribute__((address_space(3))) unsigned int*)l, 16, 0, 0);
}

// ---------------- Kernel 1: masked per-channel sum / sumsq / count ----------
// grid 256 x 256. stats layout (floats): [0..767]=sum, [768..1535]=sumsq,
// [1536]=cnt, [2048..2815]=scale, [2816..3583]=shift
__global__ void k_stats(const float* __restrict__ f, const int* __restrict__ mask,
                        float* __restrict__ stats) {
    int tid = threadIdx.x;
    int t0  = blockIdx.x * 16;
    float s0 = 0.f, s1 = 0.f, s2 = 0.f, q0 = 0.f, q1 = 0.f, q2 = 0.f;
    for (int tt = 0; tt < 16; ++tt) {
        int t = t0 + tt;
        float m = mask[t] ? 1.f : 0.f;
        const float* row = f + (size_t)t * D_;
        float x0 = row[tid];
        float x1 = row[tid + 256];
        float x2 = row[tid + 512];
        s0 += x0 * m; q0 += x0 * x0 * m;
        s1 += x1 * m; q1 += x1 * x1 * m;
        s2 += x2 * m; q2 += x2 * x2 * m;
    }
    atomicAdd(&stats[tid      ], s0);
    atomicAdd(&stats[tid + 256], s1);
    atomicAdd(&stats[tid + 512], s2);
    atomicAdd(&stats[768 + tid      ], q0);
    atomicAdd(&stats[768 + tid + 256], q1);
    atomicAdd(&stats[768 + tid + 512], q2);
    if (tid == 0) {
        int c = 0;
        for (int tt = 0; tt < 16; ++tt) c += (mask[t0 + tt] ? 1 : 0);
        atomicAdd(&stats[1536], (float)c);
    }
}

// ---------------- Kernel 1b: finalize scale/shift ---------------------------
__global__ void k_finalize(const float* __restrict__ gamma, const float* __restrict__ beta,
                           float* __restrict__ stats) {
    int d = threadIdx.x;  // 768
    float denom = fmaxf(stats[1536], 1.f);
    float mean  = stats[d] / denom;
    float var   = fmaxf(stats[768 + d] / denom - mean * mean, 0.f);
    float sc    = gamma[d] * rsqrtf(var + BN_EPS);
    stats[2048 + d] = sc;
    stats[2816 + d] = beta[d] - mean * sc;
}

// ---------------- Kernel 2: normalize+mask+cast feats, cast ff_w ------------
// grid 6144 x 256. First 3072 blocks: norm path over M_*D_/4 float4.
// Last 3072 blocks: cast ff_w (NO_*D_/4 float4).
__global__ void k_normcast(const float4* __restrict__ f4, const float4* __restrict__ w4,
                           const int* __restrict__ mask, const float* __restrict__ stats,
                           unsigned short* __restrict__ featp, unsigned short* __restrict__ wp) {
    int i = blockIdx.x * 256 + threadIdx.x;
    if (i < M_ * D_ / 4) {
        int d4 = i % (D_ / 4);
        int t  = i / (D_ / 4);
        float m = mask[t] ? 1.f : 0.f;
        float4 v = f4[i];
        int d = d4 * 4;
        float r0 = (v.x * stats[2048 + d + 0] + stats[2816 + d + 0]) * m;
        float r1 = (v.y * stats[2048 + d + 1] + stats[2816 + d + 1]) * m;
        float r2 = (v.z * stats[2048 + d + 2] + stats[2816 + d + 2]) * m;
        float r3 = (v.w * stats[2048 + d + 3] + stats[2816 + d + 3]) * m;
        ushort4 o;
        o.x = f2bf(r0); o.y = f2bf(r1); o.z = f2bf(r2); o.w = f2bf(r3);
        ((ushort4*)featp)[i] = o;
    } else {
        int j = i - M_ * D_ / 4;
        float4 v = w4[j];
        ushort4 o;
        o.x = f2bf(v.x); o.y = f2bf(v.y); o.z = f2bf(v.z); o.w = f2bf(v.w);
        ((ushort4*)wp)[j] = o;
    }
}

// ---------------- Kernel 3: FFN GEMM (h = relu(feats @ W^T + b)) ------------
// m97 structure: 128x128 tile, BK=32, linear LDS [128][32], global_load_lds
// width 16, 2 barriers per K-step. Epilogue scatters into start/end arrays
// with layout [B][L][T][DL] bf16 each.
__launch_bounds__(256)
__global__ void k_ffn(const unsigned short* __restrict__ A, const unsigned short* __restrict__ W,
                      const float* __restrict__ bias,
                      unsigned short* __restrict__ startp, unsigned short* __restrict__ endp) {
    __shared__ alignas(16) unsigned short As[128 * 32];
    __shared__ alignas(16) unsigned short Bs[128 * 32];
    int tid  = threadIdx.x;
    int bm   = blockIdx.x, bn = blockIdx.y;
    int wave = tid >> 6, lane = tid & 63;
    int wm = wave >> 1, wn = wave & 1;
    int lr = lane & 15, quad = lane >> 4;
    f32x4 acc[4][4] = {};
    const int K = D_;
    // staging geometry: tile = 128 rows x 32 cols bf16 = 8 KiB = 8 chunks x 1 KiB.
    // wave w stages chunks {2w, 2w+1} of A and of B. lane l covers
    // lds offset c*1024 + l*16  <=>  row = c*16 + l/4, colshort = (l&3)*8.
    int srow   = (lane >> 2);
    int scolsh = (lane & 3) * 8;
    for (int k0 = 0; k0 < K; k0 += 32) {
#pragma unroll
        for (int p = 0; p < 2; ++p) {
            int c   = wave * 2 + p;
            int row = c * 16 + srow;
            gload_lds16(A + (size_t)(bm * 128 + row) * K + k0 + scolsh, &As[c * 512]);
            gload_lds16(W + (size_t)(bn * 128 + row) * K + k0 + scolsh, &Bs[c * 512]);
        }
        __syncthreads();
        short8 a[4], b[4];
#pragma unroll
        for (int i = 0; i < 4; ++i) a[i] = *(const short8*)&As[(wm * 64 + i * 16 + lr) * 32 + quad * 8];
#pragma unroll
        for (int i = 0; i < 4; ++i) b[i] = *(const short8*)&Bs[(wn * 64 + i * 16 + lr) * 32 + quad * 8];
#pragma unroll
        for (int i = 0; i < 4; ++i)
#pragma unroll
            for (int j = 0; j < 4; ++j)
                acc[i][j] = __builtin_amdgcn_mfma_f32_16x16x32_bf16(a[i], b[j], acc[i][j], 0, 0, 0);
        __syncthreads();
    }
#pragma unroll
    for (int i = 0; i < 4; ++i) {
#pragma unroll
        for (int j = 0; j < 4; ++j) {
            int col  = bn * 128 + wn * 64 + j * 16 + lr;   // output channel o
            int l    = col >> 8;
            int dd   = (col >> 1) & 127;
            int cbit = col & 1;
            unsigned short* dst = cbit ? endp : startp;
            float bv = bias[col];
#pragma unroll
            for (int r = 0; r < 4; ++r) {
                int row = bm * 128 + wm * 64 + i * 16 + quad * 4 + r;  // token
                float v = acc[i][j][r] + bv;
                v = fmaxf(v, 0.f);
                int bb = row >> 9, tt = row & 511;
                dst[(((size_t)(bb * 16 + l) * 512 + tt) << 7) + dd] = f2bf(v);
            }
        }
    }
}

// ---------------- Kernel 4: biaffine scores + spans_mask (fused) ------------
// per (b,l): C[s,e] = sum_d start[s,d]*end[e,d] + label_bias[l]
// Single-buffered LDS, BK=64 (two halves of K=128), staged via
// global_load_lds width-16 with XOR-swizzle applied on the GLOBAL SOURCE side
// (rule #21: linear LDS dest + inverse-swizzled source + swizzled ds_read).
// Logical granule (row, gl) lives at LDS physical (row, gl ^ (row&7)), 16B
// granules, 8 granules/row. Staging is fully coalesced (1KiB contiguous per
// instruction, granules merely permuted within rows); fragment reads hit all
// 8 bank groups with 2 lanes/bank (free, m136). 32KiB LDS -> 4 blocks/CU.
// Also writes spans_mask for the same (b,l,s,e) tile. grid (4,4,128), block 256.
__launch_bounds__(256)
__global__ void k_biaffine(const unsigned short* __restrict__ startp,
                           const unsigned short* __restrict__ endp,
                           const int* __restrict__ mask,
                           const float* __restrict__ lbias,
                           float* __restrict__ out_scores, float* __restrict__ out_mask) {
    __shared__ alignas(16) unsigned short As[128 * 64];
    __shared__ alignas(16) unsigned short Bs[128 * 64];
    int tid = threadIdx.x;
    int bm = blockIdx.x, bn = blockIdx.y;
    int bl = blockIdx.z;  // b*16 + l
    int b  = bl >> 4;
    const unsigned short* A  = startp + (size_t)bl * 512 * 128;
    const unsigned short* Bp = endp   + (size_t)bl * 512 * 128;
    int wave = tid >> 6, lane = tid & 63;
    int wm = wave >> 1, wn = wave & 1;
    int lr = lane & 15, quad = lane >> 4;
    f32x4 acc[4][4] = {};
    // staging: chunk c (0..15) = 1KiB = rows c*8..c*8+7. lane l -> dest byte
    // c*1024 + l*16 -> (row = c*8 + l/8, physical granule gp = l&7); source
    // logical granule gl = gp ^ (row&7).
    int srow = lane >> 3;
    for (int half = 0; half < 2; ++half) {
#pragma unroll
        for (int p = 0; p < 4; ++p) {
            int c   = wave * 4 + p;
            int row = c * 8 + srow;
            int gl  = (lane & 7) ^ (row & 7);
            gload_lds16(A  + (size_t)(bm * 128 + row) * DL_ + half * 64 + gl * 8, &As[c * 512]);
            gload_lds16(Bp + (size_t)(bn * 128 + row) * DL_ + half * 64 + gl * 8, &Bs[c * 512]);
        }
        __syncthreads();
#pragma unroll
        for (int kk = 0; kk < 2; ++kk) {
            short8 a[4], bb[4];
#pragma unroll
            for (int i = 0; i < 4; ++i) {
                int row = wm * 64 + i * 16 + lr;
                int gp  = (kk * 4 + quad) ^ (row & 7);
                a[i] = *(const short8*)&As[row * 64 + gp * 8];
            }
#pragma unroll
            for (int j = 0; j < 4; ++j) {
                int row = wn * 64 + j * 16 + lr;
                int gp  = (kk * 4 + quad) ^ (row & 7);
                bb[j] = *(const short8*)&Bs[row * 64 + gp * 8];
            }
#pragma unroll
            for (int i = 0; i < 4; ++i)
#pragma unroll
                for (int j = 0; j < 4; ++j)
                    acc[i][j] = __builtin_amdgcn_mfma_f32_16x16x32_bf16(a[i], bb[j], acc[i][j], 0, 0, 0);
        }
        __syncthreads();
    }
    float lb = lbias[bl & 15];
    float* obase = out_scores + (size_t)bl * 512 * 512;
    float* mbase = out_mask   + (size_t)bl * 512 * 512;
    // start-token mask values for the 16 rows this lane owns
    float msv[4][4];
#pragma unroll
    for (int i = 0; i < 4; ++i)
#pragma unroll
        for (int r = 0; r < 4; ++r) {
            int s = bm * 128 + wm * 64 + i * 16 + quad * 4 + r;
            msv[i][r] = mask[b * 512 + s] ? 1.f : 0.f;
        }
#pragma unroll
    for (int j = 0; j < 4; ++j) {
        int e = bn * 128 + wn * 64 + j * 16 + lr;
        float me = mask[b * 512 + e] ? 1.f : 0.f;
#pragma unroll
        for (int i = 0; i < 4; ++i) {
#pragma unroll
            for (int r = 0; r < 4; ++r) {
                int s = bm * 128 + wm * 64 + i * 16 + quad * 4 + r;
                size_t off = (size_t)s * 512 + e;
                obase[off] = acc[i][j][r] + lb;
                mbase[off] = (s <= e) ? msv[i][r] * me : 0.f;
            }
        }
    }
}

extern "C" void kernel_launch(void* const* d_in, const int* in_sizes, int n_in,
                              void* d_out, int out_size, void* d_ws, size_t ws_size,
                              hipStream_t stream) {
    const float* features = (const float*)d_in[0];
    const int*   mask     = (const int*)d_in[1];
    const float* gamma    = (const float*)d_in[2];
    const float* beta     = (const float*)d_in[3];
    const float* ffw      = (const float*)d_in[4];
    const float* ffb      = (const float*)d_in[5];
    const float* lbias    = (const float*)d_in[6];

    float* out_scores = (float*)d_out;
    float* out_mask   = out_scores + (size_t)B_ * L_ * T_ * T_;  // 33554432

    char* ws = (char*)d_ws;
    float*          stats  = (float*)ws;                              // 16 KiB
    unsigned short* feats  = (unsigned short*)(ws + 16384);           // 6 MiB
    unsigned short* wbf    = (unsigned short*)(ws + 16384 + 6291456); // 6 MiB
    unsigned short* startp = (unsigned short*)(ws + 12599296);        // 16 MiB
    unsigned short* endp   = (unsigned short*)(ws + 29376512);        // 16 MiB

    hipMemsetAsync(ws, 0, 16384, stream);
    k_stats<<<256, 256, 0, stream>>>(features, mask, stats);
    k_finalize<<<1, 768, 0, stream>>>(gamma, beta, stats);
    k_normcast<<<6144, 256, 0, stream>>>((const float4*)features, (const float4*)ffw,
                                         mask, stats, feats, wbf);
    dim3 g1(32, 32);
    k_ffn<<<g1, 256, 0, stream>>>(feats, wbf, ffb, startp, endp);
    dim3 g2(4, 4, 128);
    k_biaffine<<<g2, 256, 0, stream>>>(startp, endp, mask, lbias, out_scores, out_mask);
}

// Round 3
// 378.995 us; speedup vs baseline: 1.0839x; 1.0775x over previous
//
#include <hip/hip_runtime.h>

#define B_    8
#define T_    512
#define D_    768
#define L_    16
#define DL_   128
#define NO_   4096   // L_*DL_*2
#define M_    4096   // B_*T_
#define BN_EPS 1e-5f

typedef __attribute__((ext_vector_type(8))) short short8;
typedef __attribute__((ext_vector_type(4))) float f32x4;

__device__ inline unsigned short f2bf(float x) {
    unsigned int u = __float_as_uint(x);
    unsigned int r = (u + 0x7fffu + ((u >> 16) & 1u)) >> 16;
    return (unsigned short)r;
}

// async global -> LDS, 16 bytes per lane (dest = uniform base + lane*16)
__device__ __forceinline__ void gload_lds16(const unsigned short* g, unsigned short* l) {
    __builtin_amdgcn_global_load_lds(
        (const __attribute__((address_space(1))) unsigned int*)g,
        (__attribute__((address_space(3))) unsigned int*)l, 16, 0, 0);
}

// ---------------- Kernel 1: masked per-channel sum / sumsq / count ----------
__global__ void k_stats(const float* __restrict__ f, const int* __restrict__ mask,
                        float* __restrict__ stats) {
    int tid = threadIdx.x;
    int t0  = blockIdx.x * 16;
    float s0 = 0.f, s1 = 0.f, s2 = 0.f, q0 = 0.f, q1 = 0.f, q2 = 0.f;
    for (int tt = 0; tt < 16; ++tt) {
        int t = t0 + tt;
        float m = mask[t] ? 1.f : 0.f;
        const float* row = f + (size_t)t * D_;
        float x0 = row[tid];
        float x1 = row[tid + 256];
        float x2 = row[tid + 512];
        s0 += x0 * m; q0 += x0 * x0 * m;
        s1 += x1 * m; q1 += x1 * x1 * m;
        s2 += x2 * m; q2 += x2 * x2 * m;
    }
    atomicAdd(&stats[tid      ], s0);
    atomicAdd(&stats[tid + 256], s1);
    atomicAdd(&stats[tid + 512], s2);
    atomicAdd(&stats[768 + tid      ], q0);
    atomicAdd(&stats[768 + tid + 256], q1);
    atomicAdd(&stats[768 + tid + 512], q2);
    if (tid == 0) {
        int c = 0;
        for (int tt = 0; tt < 16; ++tt) c += (mask[t0 + tt] ? 1 : 0);
        atomicAdd(&stats[1536], (float)c);
    }
}

// ---------------- Kernel 1b: finalize scale/shift ---------------------------
__global__ void k_finalize(const float* __restrict__ gamma, const float* __restrict__ beta,
                           float* __restrict__ stats) {
    int d = threadIdx.x;  // 768
    float denom = fmaxf(stats[1536], 1.f);
    float mean  = stats[d] / denom;
    float var   = fmaxf(stats[768 + d] / denom - mean * mean, 0.f);
    float sc    = gamma[d] * rsqrtf(var + BN_EPS);
    stats[2048 + d] = sc;
    stats[2816 + d] = beta[d] - mean * sc;
}

// ---------------- Kernel 2: normalize+mask+cast feats, cast ff_w ------------
__global__ void k_normcast(const float4* __restrict__ f4, const float4* __restrict__ w4,
                           const int* __restrict__ mask, const float* __restrict__ stats,
                           unsigned short* __restrict__ featp, unsigned short* __restrict__ wp) {
    int i = blockIdx.x * 256 + threadIdx.x;
    if (i < M_ * D_ / 4) {
        int d4 = i % (D_ / 4);
        int t  = i / (D_ / 4);
        float m = mask[t] ? 1.f : 0.f;
        float4 v = f4[i];
        int d = d4 * 4;
        float r0 = (v.x * stats[2048 + d + 0] + stats[2816 + d + 0]) * m;
        float r1 = (v.y * stats[2048 + d + 1] + stats[2816 + d + 1]) * m;
        float r2 = (v.z * stats[2048 + d + 2] + stats[2816 + d + 2]) * m;
        float r3 = (v.w * stats[2048 + d + 3] + stats[2816 + d + 3]) * m;
        ushort4 o;
        o.x = f2bf(r0); o.y = f2bf(r1); o.z = f2bf(r2); o.w = f2bf(r3);
        ((ushort4*)featp)[i] = o;
    } else {
        int j = i - M_ * D_ / 4;
        float4 v = w4[j];
        ushort4 o;
        o.x = f2bf(v.x); o.y = f2bf(v.y); o.z = f2bf(v.z); o.w = f2bf(v.w);
        ((ushort4*)wp)[j] = o;
    }
}

// ---------------- Kernel 3: FFN GEMM (h = relu(feats @ W^T + b)) ------------
// 4-slot counted-vmcnt pipeline (T2+T3+T4+T5 minimal form):
// 128x128 tile, BK=64, 8 waves (2Mx4N, per-wave 64x32 out, acc[4][2]).
// LDS = 4 K-tile slots x (A 16KB + B 16KB) = 128 KiB -> 1 block/CU.
// Phase t: vmcnt gate + raw s_barrier; ds_read frags (XOR-swizzled, 2-way
// free); issue 4 gloads for tile t+2 into slot (t+2)&3 (always 2 slots away
// from the one being read -> 1 barrier/phase is WAR-safe); setprio around
// the 16-MFMA cluster. vmcnt(4) = one phase's loads in flight; vmcnt(0)
// only at the last phase (nothing issued after its tile's loads).
// Swizzle: logical granule g of row r lives at physical p = g ^ (r&7);
// achieved by inverse-swizzling the GLOBAL source per lane (rule #21),
// LDS dest stays linear for global_load_lds.
__launch_bounds__(512, 2)
__global__ void k_ffn(const unsigned short* __restrict__ A, const unsigned short* __restrict__ W,
                      const float* __restrict__ bias,
                      unsigned short* __restrict__ startp, unsigned short* __restrict__ endp) {
    __shared__ alignas(16) unsigned short LA[4][8192];
    __shared__ alignas(16) unsigned short LB[4][8192];
    int tid  = threadIdx.x;
    int bm   = blockIdx.x, bn = blockIdx.y;
    int wave = tid >> 6, lane = tid & 63;
    int wm = wave >> 2, wn = wave & 3;
    int lr = lane & 15, quad = lane >> 4;
    // stage source pointers: chunk c = 2*wave+p covers rows c*8..c*8+7 (1KB).
    // lane l -> row_in_chunk = l>>3, physical granule p = l&7,
    // logical granule g = (l&7) ^ (l>>3)  (row&7 == l>>3 since chunks 8-aligned)
    int srow = lane >> 3;
    int sg   = (lane & 7) ^ srow;
    const unsigned short* asrc[2];
    const unsigned short* bsrc[2];
#pragma unroll
    for (int p = 0; p < 2; ++p) {
        int c = wave * 2 + p;
        asrc[p] = A + (size_t)(bm * 128 + c * 8 + srow) * D_ + sg * 8;
        bsrc[p] = W + (size_t)(bn * 128 + c * 8 + srow) * D_ + sg * 8;
    }
    // fragment LDS offsets (shorts): row-major [128][64] per slot, swizzled
    int aoff[4][2], boff[2][2];
#pragma unroll
    for (int i = 0; i < 4; ++i)
#pragma unroll
        for (int kk = 0; kk < 2; ++kk) {
            int row = wm * 64 + i * 16 + lr;
            aoff[i][kk] = row * 64 + ((kk * 4 + quad) ^ (row & 7)) * 8;
        }
#pragma unroll
    for (int j = 0; j < 2; ++j)
#pragma unroll
        for (int kk = 0; kk < 2; ++kk) {
            int row = wn * 32 + j * 16 + lr;
            boff[j][kk] = row * 64 + ((kk * 4 + quad) ^ (row & 7)) * 8;
        }
    f32x4 acc[4][2] = {};
    // prologue: stage tiles 0,1 into slots 0,1 (tile0's 4 gloads first)
#pragma unroll
    for (int t = 0; t < 2; ++t) {
#pragma unroll
        for (int p = 0; p < 2; ++p) {
            int c = wave * 2 + p;
            gload_lds16(asrc[p] + t * 64, &LA[t][c * 512]);
            gload_lds16(bsrc[p] + t * 64, &LB[t][c * 512]);
        }
    }
    // 12 K-tiles of 64 (K = 768)
#pragma unroll
    for (int t = 0; t < 12; ++t) {
        // RAW gate: tile t's loads are the oldest; allow the 4 issued after
        // them (phase t-1's) to stay in flight. Last phase: nothing newer.
        if (t == 11) asm volatile("s_waitcnt vmcnt(0)\ns_barrier" ::: "memory");
        else         asm volatile("s_waitcnt vmcnt(4)\ns_barrier" ::: "memory");
        const unsigned short* la = LA[t & 3];
        const unsigned short* lb = LB[t & 3];
        short8 af[4][2], bf[2][2];
#pragma unroll
        for (int i = 0; i < 4; ++i)
#pragma unroll
            for (int kk = 0; kk < 2; ++kk)
                af[i][kk] = *(const short8*)&la[aoff[i][kk]];
#pragma unroll
        for (int j = 0; j < 2; ++j)
#pragma unroll
            for (int kk = 0; kk < 2; ++kk)
                bf[j][kk] = *(const short8*)&lb[boff[j][kk]];
        if (t < 10) {
            int ss = (t + 2) & 3;
            int ko = (t + 2) * 64;
#pragma unroll
            for (int p = 0; p < 2; ++p) {
                int c = wave * 2 + p;
                gload_lds16(asrc[p] + ko, &LA[ss][c * 512]);
                gload_lds16(bsrc[p] + ko, &LB[ss][c * 512]);
            }
        }
        __builtin_amdgcn_s_setprio(1);
#pragma unroll
        for (int kk = 0; kk < 2; ++kk)
#pragma unroll
            for (int i = 0; i < 4; ++i)
#pragma unroll
                for (int j = 0; j < 2; ++j)
                    acc[i][j] = __builtin_amdgcn_mfma_f32_16x16x32_bf16(af[i][kk], bf[j][kk], acc[i][j], 0, 0, 0);
        __builtin_amdgcn_s_setprio(0);
    }
    // epilogue: bias + relu + bf16 scatter into start/end [B][L][T][DL]
#pragma unroll
    for (int i = 0; i < 4; ++i) {
#pragma unroll
        for (int j = 0; j < 2; ++j) {
            int col  = bn * 128 + wn * 32 + j * 16 + lr;   // output channel o
            int l    = col >> 8;
            int dd   = (col >> 1) & 127;
            int cbit = col & 1;
            unsigned short* dst = cbit ? endp : startp;
            float bv = bias[col];
#pragma unroll
            for (int r = 0; r < 4; ++r) {
                int row = bm * 128 + wm * 64 + i * 16 + quad * 4 + r;  // token
                float v = acc[i][j][r] + bv;
                v = fmaxf(v, 0.f);
                int bb = row >> 9, tt = row & 511;
                dst[(((size_t)(bb * 16 + l) * 512 + tt) << 7) + dd] = f2bf(v);
            }
        }
    }
}

// ---------------- Kernel 4: biaffine scores + spans_mask (fused) ------------
// Same structure as round 2 (passed); output stores now nontemporal
// (268 MB streaming, never re-read).
__launch_bounds__(256)
__global__ void k_biaffine(const unsigned short* __restrict__ startp,
                           const unsigned short* __restrict__ endp,
                           const int* __restrict__ mask,
                           const float* __restrict__ lbias,
                           float* __restrict__ out_scores, float* __restrict__ out_mask) {
    __shared__ alignas(16) unsigned short As[128 * 64];
    __shared__ alignas(16) unsigned short Bs[128 * 64];
    int tid = threadIdx.x;
    int bm = blockIdx.x, bn = blockIdx.y;
    int bl = blockIdx.z;  // b*16 + l
    int b  = bl >> 4;
    const unsigned short* A  = startp + (size_t)bl * 512 * 128;
    const unsigned short* Bp = endp   + (size_t)bl * 512 * 128;
    int wave = tid >> 6, lane = tid & 63;
    int wm = wave >> 1, wn = wave & 1;
    int lr = lane & 15, quad = lane >> 4;
    f32x4 acc[4][4] = {};
    int srow = lane >> 3;
    for (int half = 0; half < 2; ++half) {
#pragma unroll
        for (int p = 0; p < 4; ++p) {
            int c   = wave * 4 + p;
            int row = c * 8 + srow;
            int gl  = (lane & 7) ^ (row & 7);
            gload_lds16(A  + (size_t)(bm * 128 + row) * DL_ + half * 64 + gl * 8, &As[c * 512]);
            gload_lds16(Bp + (size_t)(bn * 128 + row) * DL_ + half * 64 + gl * 8, &Bs[c * 512]);
        }
        __syncthreads();
#pragma unroll
        for (int kk = 0; kk < 2; ++kk) {
            short8 a[4], bb[4];
#pragma unroll
            for (int i = 0; i < 4; ++i) {
                int row = wm * 64 + i * 16 + lr;
                int gp  = (kk * 4 + quad) ^ (row & 7);
                a[i] = *(const short8*)&As[row * 64 + gp * 8];
            }
#pragma unroll
            for (int j = 0; j < 4; ++j) {
                int row = wn * 64 + j * 16 + lr;
                int gp  = (kk * 4 + quad) ^ (row & 7);
                bb[j] = *(const short8*)&Bs[row * 64 + gp * 8];
            }
#pragma unroll
            for (int i = 0; i < 4; ++i)
#pragma unroll
                for (int j = 0; j < 4; ++j)
                    acc[i][j] = __builtin_amdgcn_mfma_f32_16x16x32_bf16(a[i], bb[j], acc[i][j], 0, 0, 0);
        }
        __syncthreads();
    }
    float lb = lbias[bl & 15];
    float* obase = out_scores + (size_t)bl * 512 * 512;
    float* mbase = out_mask   + (size_t)bl * 512 * 512;
    float msv[4][4];
#pragma unroll
    for (int i = 0; i < 4; ++i)
#pragma unroll
        for (int r = 0; r < 4; ++r) {
            int s = bm * 128 + wm * 64 + i * 16 + quad * 4 + r;
            msv[i][r] = mask[b * 512 + s] ? 1.f : 0.f;
        }
#pragma unroll
    for (int j = 0; j < 4; ++j) {
        int e = bn * 128 + wn * 64 + j * 16 + lr;
        float me = mask[b * 512 + e] ? 1.f : 0.f;
#pragma unroll
        for (int i = 0; i < 4; ++i) {
#pragma unroll
            for (int r = 0; r < 4; ++r) {
                int s = bm * 128 + wm * 64 + i * 16 + quad * 4 + r;
                size_t off = (size_t)s * 512 + e;
                __builtin_nontemporal_store(acc[i][j][r] + lb, &obase[off]);
                __builtin_nontemporal_store((s <= e) ? msv[i][r] * me : 0.f, &mbase[off]);
            }
        }
    }
}

extern "C" void kernel_launch(void* const* d_in, const int* in_sizes, int n_in,
                              void* d_out, int out_size, void* d_ws, size_t ws_size,
                              hipStream_t stream) {
    const float* features = (const float*)d_in[0];
    const int*   mask     = (const int*)d_in[1];
    const float* gamma    = (const float*)d_in[2];
    const float* beta     = (const float*)d_in[3];
    const float* ffw      = (const float*)d_in[4];
    const float* ffb      = (const float*)d_in[5];
    const float* lbias    = (const float*)d_in[6];

    float* out_scores = (float*)d_out;
    float* out_mask   = out_scores + (size_t)B_ * L_ * T_ * T_;  // 33554432

    char* ws = (char*)d_ws;
    float*          stats  = (float*)ws;                              // 16 KiB
    unsigned short* feats  = (unsigned short*)(ws + 16384);           // 6 MiB
    unsigned short* wbf    = (unsigned short*)(ws + 16384 + 6291456); // 6 MiB
    unsigned short* startp = (unsigned short*)(ws + 12599296);        // 16 MiB
    unsigned short* endp   = (unsigned short*)(ws + 29376512);        // 16 MiB

    hipMemsetAsync(ws, 0, 16384, stream);
    k_stats<<<256, 256, 0, stream>>>(features, mask, stats);
    k_finalize<<<1, 768, 0, stream>>>(gamma, beta, stats);
    k_normcast<<<6144, 256, 0, stream>>>((const float4*)features, (const float4*)ffw,
                                         mask, stats, feats, wbf);
    dim3 g1(32, 32);
    k_ffn<<<g1, 512, 0, stream>>>(feats, wbf, ffb, startp, endp);
    dim3 g2(4, 4, 128);
    k_biaffine<<<g2, 256, 0, stream>>>(startp, endp, mask, lbias, out_scores, out_mask);
}

// Round 4
// 358.524 us; speedup vs baseline: 1.1458x; 1.0571x over previous
//
#include <hip/hip_runtime.h>

#define B_    8
#define T_    512
#define D_    768
#define L_    16
#define DL_   128
#define NO_   4096   // L_*DL_*2
#define M_    4096   // B_*T_
#define BN_EPS 1e-5f

typedef __attribute__((ext_vector_type(8))) short short8;
typedef __attribute__((ext_vector_type(4))) float f32x4;
typedef __attribute__((ext_vector_type(2))) float f32x2;

__device__ inline unsigned short f2bf(float x) {
    unsigned int u = __float_as_uint(x);
    unsigned int r = (u + 0x7fffu + ((u >> 16) & 1u)) >> 16;
    return (unsigned short)r;
}

// async global -> LDS, 16 bytes per lane (dest = uniform base + lane*16)
__device__ __forceinline__ void gload_lds16(const unsigned short* g, unsigned short* l) {
    __builtin_amdgcn_global_load_lds(
        (const __attribute__((address_space(1))) unsigned int*)g,
        (__attribute__((address_space(3))) unsigned int*)l, 16, 0, 0);
}

// ---------------- Kernel 1: masked per-channel sum / sumsq / count ----------
__global__ void k_stats(const float* __restrict__ f, const int* __restrict__ mask,
                        float* __restrict__ stats) {
    int tid = threadIdx.x;
    int t0  = blockIdx.x * 16;
    float s0 = 0.f, s1 = 0.f, s2 = 0.f, q0 = 0.f, q1 = 0.f, q2 = 0.f;
    for (int tt = 0; tt < 16; ++tt) {
        int t = t0 + tt;
        float m = mask[t] ? 1.f : 0.f;
        const float* row = f + (size_t)t * D_;
        float x0 = row[tid];
        float x1 = row[tid + 256];
        float x2 = row[tid + 512];
        s0 += x0 * m; q0 += x0 * x0 * m;
        s1 += x1 * m; q1 += x1 * x1 * m;
        s2 += x2 * m; q2 += x2 * x2 * m;
    }
    atomicAdd(&stats[tid      ], s0);
    atomicAdd(&stats[tid + 256], s1);
    atomicAdd(&stats[tid + 512], s2);
    atomicAdd(&stats[768 + tid      ], q0);
    atomicAdd(&stats[768 + tid + 256], q1);
    atomicAdd(&stats[768 + tid + 512], q2);
    if (tid == 0) {
        int c = 0;
        for (int tt = 0; tt < 16; ++tt) c += (mask[t0 + tt] ? 1 : 0);
        atomicAdd(&stats[1536], (float)c);
    }
}

// ---------------- Kernel 1b: finalize scale/shift ---------------------------
__global__ void k_finalize(const float* __restrict__ gamma, const float* __restrict__ beta,
                           float* __restrict__ stats) {
    int d = threadIdx.x;  // 768
    float denom = fmaxf(stats[1536], 1.f);
    float mean  = stats[d] / denom;
    float var   = fmaxf(stats[768 + d] / denom - mean * mean, 0.f);
    float sc    = gamma[d] * rsqrtf(var + BN_EPS);
    stats[2048 + d] = sc;
    stats[2816 + d] = beta[d] - mean * sc;
}

// ---------------- Kernel 2: normalize+mask+cast feats, cast ff_w ------------
__global__ void k_normcast(const float4* __restrict__ f4, const float4* __restrict__ w4,
                           const int* __restrict__ mask, const float* __restrict__ stats,
                           unsigned short* __restrict__ featp, unsigned short* __restrict__ wp) {
    int i = blockIdx.x * 256 + threadIdx.x;
    if (i < M_ * D_ / 4) {
        int d4 = i % (D_ / 4);
        int t  = i / (D_ / 4);
        float m = mask[t] ? 1.f : 0.f;
        float4 v = f4[i];
        int d = d4 * 4;
        float r0 = (v.x * stats[2048 + d + 0] + stats[2816 + d + 0]) * m;
        float r1 = (v.y * stats[2048 + d + 1] + stats[2816 + d + 1]) * m;
        float r2 = (v.z * stats[2048 + d + 2] + stats[2816 + d + 2]) * m;
        float r3 = (v.w * stats[2048 + d + 3] + stats[2816 + d + 3]) * m;
        ushort4 o;
        o.x = f2bf(r0); o.y = f2bf(r1); o.z = f2bf(r2); o.w = f2bf(r3);
        ((ushort4*)featp)[i] = o;
    } else {
        int j = i - M_ * D_ / 4;
        float4 v = w4[j];
        ushort4 o;
        o.x = f2bf(v.x); o.y = f2bf(v.y); o.z = f2bf(v.z); o.w = f2bf(v.w);
        ((ushort4*)wp)[j] = o;
    }
}

// ---------------- Kernel 3: FFN GEMM (h = relu(feats @ W^T + b)) ------------
// 4-slot counted-vmcnt pipeline (round 3, passed). Grid flattened to 1D with
// XCD-affine decode: xcd = wgid&7 owns a 4-row bm stripe -> its A panels stay
// L2-resident (round-robin hw dispatch assumption, perf-only).
__launch_bounds__(512, 2)
__global__ void k_ffn(const unsigned short* __restrict__ A, const unsigned short* __restrict__ W,
                      const float* __restrict__ bias,
                      unsigned short* __restrict__ startp, unsigned short* __restrict__ endp) {
    __shared__ alignas(16) unsigned short LA[4][8192];
    __shared__ alignas(16) unsigned short LB[4][8192];
    int h   = blockIdx.x;
    int xcd = h & 7, q = h >> 3;          // q in [0,128)
    int bm  = xcd * 4 + (q >> 5);         // 4 bm panels per XCD
    int bn  = q & 31;
    int tid  = threadIdx.x;
    int wave = tid >> 6, lane = tid & 63;
    int wm = wave >> 2, wn = wave & 3;
    int lr = lane & 15, quad = lane >> 4;
    int srow = lane >> 3;
    int sg   = (lane & 7) ^ srow;
    const unsigned short* asrc[2];
    const unsigned short* bsrc[2];
#pragma unroll
    for (int p = 0; p < 2; ++p) {
        int c = wave * 2 + p;
        asrc[p] = A + (size_t)(bm * 128 + c * 8 + srow) * D_ + sg * 8;
        bsrc[p] = W + (size_t)(bn * 128 + c * 8 + srow) * D_ + sg * 8;
    }
    int aoff[4][2], boff[2][2];
#pragma unroll
    for (int i = 0; i < 4; ++i)
#pragma unroll
        for (int kk = 0; kk < 2; ++kk) {
            int row = wm * 64 + i * 16 + lr;
            aoff[i][kk] = row * 64 + ((kk * 4 + quad) ^ (row & 7)) * 8;
        }
#pragma unroll
    for (int j = 0; j < 2; ++j)
#pragma unroll
        for (int kk = 0; kk < 2; ++kk) {
            int row = wn * 32 + j * 16 + lr;
            boff[j][kk] = row * 64 + ((kk * 4 + quad) ^ (row & 7)) * 8;
        }
    f32x4 acc[4][2] = {};
#pragma unroll
    for (int t = 0; t < 2; ++t) {
#pragma unroll
        for (int p = 0; p < 2; ++p) {
            int c = wave * 2 + p;
            gload_lds16(asrc[p] + t * 64, &LA[t][c * 512]);
            gload_lds16(bsrc[p] + t * 64, &LB[t][c * 512]);
        }
    }
#pragma unroll
    for (int t = 0; t < 12; ++t) {
        if (t == 11) asm volatile("s_waitcnt vmcnt(0)\ns_barrier" ::: "memory");
        else         asm volatile("s_waitcnt vmcnt(4)\ns_barrier" ::: "memory");
        const unsigned short* la = LA[t & 3];
        const unsigned short* lb = LB[t & 3];
        short8 af[4][2], bf[2][2];
#pragma unroll
        for (int i = 0; i < 4; ++i)
#pragma unroll
            for (int kk = 0; kk < 2; ++kk)
                af[i][kk] = *(const short8*)&la[aoff[i][kk]];
#pragma unroll
        for (int j = 0; j < 2; ++j)
#pragma unroll
            for (int kk = 0; kk < 2; ++kk)
                bf[j][kk] = *(const short8*)&lb[boff[j][kk]];
        if (t < 10) {
            int ss = (t + 2) & 3;
            int ko = (t + 2) * 64;
#pragma unroll
            for (int p = 0; p < 2; ++p) {
                int c = wave * 2 + p;
                gload_lds16(asrc[p] + ko, &LA[ss][c * 512]);
                gload_lds16(bsrc[p] + ko, &LB[ss][c * 512]);
            }
        }
        __builtin_amdgcn_s_setprio(1);
#pragma unroll
        for (int kk = 0; kk < 2; ++kk)
#pragma unroll
            for (int i = 0; i < 4; ++i)
#pragma unroll
                for (int j = 0; j < 2; ++j)
                    acc[i][j] = __builtin_amdgcn_mfma_f32_16x16x32_bf16(af[i][kk], bf[j][kk], acc[i][j], 0, 0, 0);
        __builtin_amdgcn_s_setprio(0);
    }
#pragma unroll
    for (int i = 0; i < 4; ++i) {
#pragma unroll
        for (int j = 0; j < 2; ++j) {
            int col  = bn * 128 + wn * 32 + j * 16 + lr;
            int l    = col >> 8;
            int dd   = (col >> 1) & 127;
            int cbit = col & 1;
            unsigned short* dst = cbit ? endp : startp;
            float bv = bias[col];
#pragma unroll
            for (int r = 0; r < 4; ++r) {
                int row = bm * 128 + wm * 64 + i * 16 + quad * 4 + r;
                float v = acc[i][j][r] + bv;
                v = fmaxf(v, 0.f);
                int bb = row >> 9, tt = row & 511;
                dst[(((size_t)(bb * 16 + l) * 512 + tt) << 7) + dd] = f2bf(v);
            }
        }
    }
}

// ---------------- Kernel 4: biaffine scores + spans_mask (fused) ------------
// Compute loop = round 2/3 (passed twice). New:
//  (a) 1D grid with XCD-affine decode: each XCD owns 16 whole bl planes ->
//      start/end panels L2-resident (kills ~8x read amplification).
//  (b) Coalesced epilogue: acc -> LDS (reusing staging buffer) -> nontemporal
//      512B-segment row writes (64 lanes x float2). Full-line NT streams,
//      no partial-line scatter. Two 64-row halves to fit 33KB LDS.
__launch_bounds__(256)
__global__ void k_biaffine(const unsigned short* __restrict__ startp,
                           const unsigned short* __restrict__ endp,
                           const int* __restrict__ mask,
                           const float* __restrict__ lbias,
                           float* __restrict__ out_scores, float* __restrict__ out_mask) {
    // smem: staging As/Bs (32KB) aliased with epilogue Cs[64][132] f32 (33KB)
    __shared__ alignas(16) float smemf[64 * 132];
    unsigned short* As = (unsigned short*)smemf;          // 128*64 shorts
    unsigned short* Bs = As + 128 * 64;
    float* Cs = smemf;
    int hgrid = blockIdx.x;
    int xcd = hgrid & 7, q = hgrid >> 3;  // q in [0,256)
    int bl  = xcd * 16 + (q >> 4);        // 16 bl planes per XCD
    int inner = q & 15;
    int bm = inner & 3, bn = inner >> 2;
    int b  = bl >> 4;
    int tid = threadIdx.x;
    const unsigned short* A  = startp + (size_t)bl * 512 * 128;
    const unsigned short* Bp = endp   + (size_t)bl * 512 * 128;
    int wave = tid >> 6, lane = tid & 63;
    int wm = wave >> 1, wn = wave & 1;
    int lr = lane & 15, quad = lane >> 4;
    f32x4 acc[4][4] = {};
    int srow = lane >> 3;
    for (int half = 0; half < 2; ++half) {
#pragma unroll
        for (int p = 0; p < 4; ++p) {
            int c   = wave * 4 + p;
            int row = c * 8 + srow;
            int gl  = (lane & 7) ^ (row & 7);
            gload_lds16(A  + (size_t)(bm * 128 + row) * DL_ + half * 64 + gl * 8, &As[c * 512]);
            gload_lds16(Bp + (size_t)(bn * 128 + row) * DL_ + half * 64 + gl * 8, &Bs[c * 512]);
        }
        __syncthreads();
#pragma unroll
        for (int kk = 0; kk < 2; ++kk) {
            short8 a[4], bb[4];
#pragma unroll
            for (int i = 0; i < 4; ++i) {
                int row = wm * 64 + i * 16 + lr;
                int gp  = (kk * 4 + quad) ^ (row & 7);
                a[i] = *(const short8*)&As[row * 64 + gp * 8];
            }
#pragma unroll
            for (int j = 0; j < 4; ++j) {
                int row = wn * 64 + j * 16 + lr;
                int gp  = (kk * 4 + quad) ^ (row & 7);
                bb[j] = *(const short8*)&Bs[row * 64 + gp * 8];
            }
#pragma unroll
            for (int i = 0; i < 4; ++i)
#pragma unroll
                for (int j = 0; j < 4; ++j)
                    acc[i][j] = __builtin_amdgcn_mfma_f32_16x16x32_bf16(a[i], bb[j], acc[i][j], 0, 0, 0);
        }
        __syncthreads();
    }
    float lb = lbias[bl & 15];
    float* obase = out_scores + (size_t)bl * 512 * 512;
    float* mbase = out_mask   + (size_t)bl * 512 * 512;
    // per-lane end-token columns (fixed): e0,e1 = bn*128 + lane*2 (+1)
    int e0 = bn * 128 + lane * 2;
    float me0 = mask[b * 512 + e0    ] ? 1.f : 0.f;
    float me1 = mask[b * 512 + e0 + 1] ? 1.f : 0.f;
    for (int hh = 0; hh < 2; ++hh) {
        // writer phase: waves with wm==hh deposit their 64x128 acc block
        if (wm == hh) {
#pragma unroll
            for (int i = 0; i < 4; ++i)
#pragma unroll
                for (int j = 0; j < 4; ++j)
#pragma unroll
                    for (int r = 0; r < 4; ++r)
                        Cs[(i * 16 + quad * 4 + r) * 132 + wn * 64 + j * 16 + lr] = acc[i][j][r];
        }
        __syncthreads();
        // read-out: all 4 waves, 16 rows each, 512B contiguous NT stores
#pragma unroll
        for (int rr = 0; rr < 16; ++rr) {
            int rloc = wave * 16 + rr;
            int s = bm * 128 + hh * 64 + rloc;
            f32x2 v = *(const f32x2*)&Cs[rloc * 132 + lane * 2];
            v.x += lb; v.y += lb;
            float ms = mask[b * 512 + s] ? 1.f : 0.f;
            f32x2 mk;
            mk.x = (s <= e0    ) ? ms * me0 : 0.f;
            mk.y = (s <= e0 + 1) ? ms * me1 : 0.f;
            size_t off = (size_t)s * 512 + e0;
            __builtin_nontemporal_store(v,  (f32x2*)&obase[off]);
            __builtin_nontemporal_store(mk, (f32x2*)&mbase[off]);
        }
        __syncthreads();
    }
}

extern "C" void kernel_launch(void* const* d_in, const int* in_sizes, int n_in,
                              void* d_out, int out_size, void* d_ws, size_t ws_size,
                              hipStream_t stream) {
    const float* features = (const float*)d_in[0];
    const int*   mask     = (const int*)d_in[1];
    const float* gamma    = (const float*)d_in[2];
    const float* beta     = (const float*)d_in[3];
    const float* ffw      = (const float*)d_in[4];
    const float* ffb      = (const float*)d_in[5];
    const float* lbias    = (const float*)d_in[6];

    float* out_scores = (float*)d_out;
    float* out_mask   = out_scores + (size_t)B_ * L_ * T_ * T_;  // 33554432

    char* ws = (char*)d_ws;
    float*          stats  = (float*)ws;                              // 16 KiB
    unsigned short* feats  = (unsigned short*)(ws + 16384);           // 6 MiB
    unsigned short* wbf    = (unsigned short*)(ws + 16384 + 6291456); // 6 MiB
    unsigned short* startp = (unsigned short*)(ws + 12599296);        // 16 MiB
    unsigned short* endp   = (unsigned short*)(ws + 29376512);        // 16 MiB

    hipMemsetAsync(ws, 0, 16384, stream);
    k_stats<<<256, 256, 0, stream>>>(features, mask, stats);
    k_finalize<<<1, 768, 0, stream>>>(gamma, beta, stats);
    k_normcast<<<6144, 256, 0, stream>>>((const float4*)features, (const float4*)ffw,
                                         mask, stats, feats, wbf);
    k_ffn<<<1024, 512, 0, stream>>>(feats, wbf, ffb, startp, endp);
    k_biaffine<<<2048, 256, 0, stream>>>(startp, endp, mask, lbias, out_scores, out_mask);
}

// Round 5
// 351.288 us; speedup vs baseline: 1.1694x; 1.0206x over previous
//
#include <hip/hip_runtime.h>

#define B_    8
#define T_    512
#define D_    768
#define L_    16
#define DL_   128
#define NO_   4096   // L_*DL_*2
#define M_    4096   // B_*T_
#define BN_EPS 1e-5f

typedef __attribute__((ext_vector_type(8))) short short8;
typedef __attribute__((ext_vector_type(4))) float f32x4;
typedef __attribute__((ext_vector_type(2))) float f32x2;

__device__ inline unsigned short f2bf(float x) {
    unsigned int u = __float_as_uint(x);
    unsigned int r = (u + 0x7fffu + ((u >> 16) & 1u)) >> 16;
    return (unsigned short)r;
}

// async global -> LDS, 16 bytes per lane (dest = uniform base + lane*16)
__device__ __forceinline__ void gload_lds16(const unsigned short* g, unsigned short* l) {
    __builtin_amdgcn_global_load_lds(
        (const __attribute__((address_space(1))) unsigned int*)g,
        (__attribute__((address_space(3))) unsigned int*)l, 16, 0, 0);
}

// ---------------- Kernel 1: masked per-channel sum / sumsq / count ----------
__global__ void k_stats(const float* __restrict__ f, const int* __restrict__ mask,
                        float* __restrict__ stats) {
    int tid = threadIdx.x;
    int t0  = blockIdx.x * 16;
    float s0 = 0.f, s1 = 0.f, s2 = 0.f, q0 = 0.f, q1 = 0.f, q2 = 0.f;
    for (int tt = 0; tt < 16; ++tt) {
        int t = t0 + tt;
        float m = mask[t] ? 1.f : 0.f;
        const float* row = f + (size_t)t * D_;
        float x0 = row[tid];
        float x1 = row[tid + 256];
        float x2 = row[tid + 512];
        s0 += x0 * m; q0 += x0 * x0 * m;
        s1 += x1 * m; q1 += x1 * x1 * m;
        s2 += x2 * m; q2 += x2 * x2 * m;
    }
    atomicAdd(&stats[tid      ], s0);
    atomicAdd(&stats[tid + 256], s1);
    atomicAdd(&stats[tid + 512], s2);
    atomicAdd(&stats[768 + tid      ], q0);
    atomicAdd(&stats[768 + tid + 256], q1);
    atomicAdd(&stats[768 + tid + 512], q2);
    if (tid == 0) {
        int c = 0;
        for (int tt = 0; tt < 16; ++tt) c += (mask[t0 + tt] ? 1 : 0);
        atomicAdd(&stats[1536], (float)c);
    }
}

// ---------------- Kernel 2: normalize+mask+cast feats, cast ff_w ------------
// k_finalize folded in: each norm-path thread derives scale/shift for its 4
// channels from the raw sums (identical expressions -> bit-identical output;
// stats is L2-resident, kernel stays memory-bound).
__global__ void k_normcast(const float4* __restrict__ f4, const float4* __restrict__ w4,
                           const int* __restrict__ mask, const float* __restrict__ stats,
                           const float* __restrict__ gamma, const float* __restrict__ beta,
                           unsigned short* __restrict__ featp, unsigned short* __restrict__ wp) {
    int i = blockIdx.x * 256 + threadIdx.x;
    if (i < M_ * D_ / 4) {
        int d4 = i % (D_ / 4);
        int t  = i / (D_ / 4);
        float m = mask[t] ? 1.f : 0.f;
        float4 v = f4[i];
        int d = d4 * 4;
        float denom = fmaxf(stats[1536], 1.f);
        float sc[4], sh[4];
#pragma unroll
        for (int c = 0; c < 4; ++c) {
            float mean = stats[d + c] / denom;
            float var  = fmaxf(stats[768 + d + c] / denom - mean * mean, 0.f);
            float s    = gamma[d + c] * rsqrtf(var + BN_EPS);
            sc[c] = s;
            sh[c] = beta[d + c] - mean * s;
        }
        float r0 = (v.x * sc[0] + sh[0]) * m;
        float r1 = (v.y * sc[1] + sh[1]) * m;
        float r2 = (v.z * sc[2] + sh[2]) * m;
        float r3 = (v.w * sc[3] + sh[3]) * m;
        ushort4 o;
        o.x = f2bf(r0); o.y = f2bf(r1); o.z = f2bf(r2); o.w = f2bf(r3);
        ((ushort4*)featp)[i] = o;
    } else {
        int j = i - M_ * D_ / 4;
        float4 v = w4[j];
        ushort4 o;
        o.x = f2bf(v.x); o.y = f2bf(v.y); o.z = f2bf(v.z); o.w = f2bf(v.w);
        ((ushort4*)wp)[j] = o;
    }
}

// ---------------- Kernel 3: FFN GEMM (h = relu(feats @ W^T + b)) ------------
// 4-slot counted-vmcnt pipeline (rounds 3/4, passed). New: coalesced epilogue.
// The raw scatter wrote 16B slivers (start/end interleave at col parity).
// Now: deposit bf16 C-tile into LDS de-interleaved [row][a*64+dd'] (row
// stride 136 shorts -> 16B-aligned reads, 2-way banks = free), then read out
// as uint4 per lane with 8 lanes covering one full 128B dst run:
// every store instruction = 8 full 128B segments. Cached stores (biaffine
// re-reads these from L2).
__launch_bounds__(512, 2)
__global__ void k_ffn(const unsigned short* __restrict__ A, const unsigned short* __restrict__ W,
                      const float* __restrict__ bias,
                      unsigned short* __restrict__ startp, unsigned short* __restrict__ endp) {
    __shared__ alignas(16) unsigned short LA[4][8192];
    __shared__ alignas(16) unsigned short LB[4][8192];
    int h   = blockIdx.x;
    int xcd = h & 7, q = h >> 3;          // q in [0,128)
    int bm  = xcd * 4 + (q >> 5);         // 4 bm panels per XCD
    int bn  = q & 31;
    int tid  = threadIdx.x;
    int wave = tid >> 6, lane = tid & 63;
    int wm = wave >> 2, wn = wave & 3;
    int lr = lane & 15, quad = lane >> 4;
    int srow = lane >> 3;
    int sg   = (lane & 7) ^ srow;
    const unsigned short* asrc[2];
    const unsigned short* bsrc[2];
#pragma unroll
    for (int p = 0; p < 2; ++p) {
        int c = wave * 2 + p;
        asrc[p] = A + (size_t)(bm * 128 + c * 8 + srow) * D_ + sg * 8;
        bsrc[p] = W + (size_t)(bn * 128 + c * 8 + srow) * D_ + sg * 8;
    }
    int aoff[4][2], boff[2][2];
#pragma unroll
    for (int i = 0; i < 4; ++i)
#pragma unroll
        for (int kk = 0; kk < 2; ++kk) {
            int row = wm * 64 + i * 16 + lr;
            aoff[i][kk] = row * 64 + ((kk * 4 + quad) ^ (row & 7)) * 8;
        }
#pragma unroll
    for (int j = 0; j < 2; ++j)
#pragma unroll
        for (int kk = 0; kk < 2; ++kk) {
            int row = wn * 32 + j * 16 + lr;
            boff[j][kk] = row * 64 + ((kk * 4 + quad) ^ (row & 7)) * 8;
        }
    f32x4 acc[4][2] = {};
#pragma unroll
    for (int t = 0; t < 2; ++t) {
#pragma unroll
        for (int p = 0; p < 2; ++p) {
            int c = wave * 2 + p;
            gload_lds16(asrc[p] + t * 64, &LA[t][c * 512]);
            gload_lds16(bsrc[p] + t * 64, &LB[t][c * 512]);
        }
    }
#pragma unroll
    for (int t = 0; t < 12; ++t) {
        if (t == 11) asm volatile("s_waitcnt vmcnt(0)\ns_barrier" ::: "memory");
        else         asm volatile("s_waitcnt vmcnt(4)\ns_barrier" ::: "memory");
        const unsigned short* la = LA[t & 3];
        const unsigned short* lb = LB[t & 3];
        short8 af[4][2], bf[2][2];
#pragma unroll
        for (int i = 0; i < 4; ++i)
#pragma unroll
            for (int kk = 0; kk < 2; ++kk)
                af[i][kk] = *(const short8*)&la[aoff[i][kk]];
#pragma unroll
        for (int j = 0; j < 2; ++j)
#pragma unroll
            for (int kk = 0; kk < 2; ++kk)
                bf[j][kk] = *(const short8*)&lb[boff[j][kk]];
        if (t < 10) {
            int ss = (t + 2) & 3;
            int ko = (t + 2) * 64;
#pragma unroll
            for (int p = 0; p < 2; ++p) {
                int c = wave * 2 + p;
                gload_lds16(asrc[p] + ko, &LA[ss][c * 512]);
                gload_lds16(bsrc[p] + ko, &LB[ss][c * 512]);
            }
        }
        __builtin_amdgcn_s_setprio(1);
#pragma unroll
        for (int kk = 0; kk < 2; ++kk)
#pragma unroll
            for (int i = 0; i < 4; ++i)
#pragma unroll
                for (int j = 0; j < 2; ++j)
                    acc[i][j] = __builtin_amdgcn_mfma_f32_16x16x32_bf16(af[i][kk], bf[j][kk], acc[i][j], 0, 0, 0);
        __builtin_amdgcn_s_setprio(0);
    }
    // ---- epilogue: LDS bounce, de-interleaved, then 128B-run stores ----
    __syncthreads();                       // all MFMA frag reads done; reuse LA
    unsigned short* C16 = &LA[0][0];       // 128 rows x 136 shorts = 34.8 KB
#pragma unroll
    for (int i = 0; i < 4; ++i) {
#pragma unroll
        for (int j = 0; j < 2; ++j) {
            int col_local = wn * 32 + j * 16 + lr;           // 0..127
            float bv = bias[bn * 128 + col_local];
            int a   = col_local & 1;                          // start/end
            int ddp = col_local >> 1;                         // 0..63
#pragma unroll
            for (int r = 0; r < 4; ++r) {
                int row = wm * 64 + i * 16 + quad * 4 + r;    // 0..127
                float v = fmaxf(acc[i][j][r] + bv, 0.f);
                C16[row * 136 + a * 64 + ddp] = f2bf(v);
            }
        }
    }
    __syncthreads();
    int bb     = bm >> 2;
    int l      = bn >> 1;
    int ddbase = (bn & 1) * 64;
#pragma unroll
    for (int it = 0; it < 4; ++it) {
        int flat  = it * 512 + tid;        // 0..2047
        int piece = flat & 7;              // which 16B of the 128B run
        int run   = flat >> 3;             // 0..255 = (row, a)
        int a     = run & 1;
        int row   = run >> 1;              // 0..127
        int tt    = (bm & 3) * 128 + row;
        uint4 v = *(const uint4*)&C16[row * 136 + a * 64 + piece * 8];
        unsigned short* dst = a ? endp : startp;
        size_t off = ((size_t)(bb * 16 + l) * 512 + tt) * 128 + ddbase + piece * 8;
        *(uint4*)&dst[off] = v;
    }
}

// ---------------- Kernel 4: biaffine scores + spans_mask (fused) ------------
// Round 4 version (passed): XCD-affine decode, LDS-transposed epilogue with
// full-line NT streams.
__launch_bounds__(256)
__global__ void k_biaffine(const unsigned short* __restrict__ startp,
                           const unsigned short* __restrict__ endp,
                           const int* __restrict__ mask,
                           const float* __restrict__ lbias,
                           float* __restrict__ out_scores, float* __restrict__ out_mask) {
    __shared__ alignas(16) float smemf[64 * 132];
    unsigned short* As = (unsigned short*)smemf;          // 128*64 shorts
    unsigned short* Bs = As + 128 * 64;
    float* Cs = smemf;
    int hgrid = blockIdx.x;
    int xcd = hgrid & 7, q = hgrid >> 3;  // q in [0,256)
    int bl  = xcd * 16 + (q >> 4);        // 16 bl planes per XCD
    int inner = q & 15;
    int bm = inner & 3, bn = inner >> 2;
    int b  = bl >> 4;
    int tid = threadIdx.x;
    const unsigned short* A  = startp + (size_t)bl * 512 * 128;
    const unsigned short* Bp = endp   + (size_t)bl * 512 * 128;
    int wave = tid >> 6, lane = tid & 63;
    int wm = wave >> 1, wn = wave & 1;
    int lr = lane & 15, quad = lane >> 4;
    f32x4 acc[4][4] = {};
    int srow = lane >> 3;
    for (int half = 0; half < 2; ++half) {
#pragma unroll
        for (int p = 0; p < 4; ++p) {
            int c   = wave * 4 + p;
            int row = c * 8 + srow;
            int gl  = (lane & 7) ^ (row & 7);
            gload_lds16(A  + (size_t)(bm * 128 + row) * DL_ + half * 64 + gl * 8, &As[c * 512]);
            gload_lds16(Bp + (size_t)(bn * 128 + row) * DL_ + half * 64 + gl * 8, &Bs[c * 512]);
        }
        __syncthreads();
#pragma unroll
        for (int kk = 0; kk < 2; ++kk) {
            short8 a[4], bb[4];
#pragma unroll
            for (int i = 0; i < 4; ++i) {
                int row = wm * 64 + i * 16 + lr;
                int gp  = (kk * 4 + quad) ^ (row & 7);
                a[i] = *(const short8*)&As[row * 64 + gp * 8];
            }
#pragma unroll
            for (int j = 0; j < 4; ++j) {
                int row = wn * 64 + j * 16 + lr;
                int gp  = (kk * 4 + quad) ^ (row & 7);
                bb[j] = *(const short8*)&Bs[row * 64 + gp * 8];
            }
#pragma unroll
            for (int i = 0; i < 4; ++i)
#pragma unroll
                for (int j = 0; j < 4; ++j)
                    acc[i][j] = __builtin_amdgcn_mfma_f32_16x16x32_bf16(a[i], bb[j], acc[i][j], 0, 0, 0);
        }
        __syncthreads();
    }
    float lb = lbias[bl & 15];
    float* obase = out_scores + (size_t)bl * 512 * 512;
    float* mbase = out_mask   + (size_t)bl * 512 * 512;
    int e0 = bn * 128 + lane * 2;
    float me0 = mask[b * 512 + e0    ] ? 1.f : 0.f;
    float me1 = mask[b * 512 + e0 + 1] ? 1.f : 0.f;
    for (int hh = 0; hh < 2; ++hh) {
        if (wm == hh) {
#pragma unroll
            for (int i = 0; i < 4; ++i)
#pragma unroll
                for (int j = 0; j < 4; ++j)
#pragma unroll
                    for (int r = 0; r < 4; ++r)
                        Cs[(i * 16 + quad * 4 + r) * 132 + wn * 64 + j * 16 + lr] = acc[i][j][r];
        }
        __syncthreads();
#pragma unroll
        for (int rr = 0; rr < 16; ++rr) {
            int rloc = wave * 16 + rr;
            int s = bm * 128 + hh * 64 + rloc;
            f32x2 v = *(const f32x2*)&Cs[rloc * 132 + lane * 2];
            v.x += lb; v.y += lb;
            float ms = mask[b * 512 + s] ? 1.f : 0.f;
            f32x2 mk;
            mk.x = (s <= e0    ) ? ms * me0 : 0.f;
            mk.y = (s <= e0 + 1) ? ms * me1 : 0.f;
            size_t off = (size_t)s * 512 + e0;
            __builtin_nontemporal_store(v,  (f32x2*)&obase[off]);
            __builtin_nontemporal_store(mk, (f32x2*)&mbase[off]);
        }
        __syncthreads();
    }
}

extern "C" void kernel_launch(void* const* d_in, const int* in_sizes, int n_in,
                              void* d_out, int out_size, void* d_ws, size_t ws_size,
                              hipStream_t stream) {
    const float* features = (const float*)d_in[0];
    const int*   mask     = (const int*)d_in[1];
    const float* gamma    = (const float*)d_in[2];
    const float* beta     = (const float*)d_in[3];
    const float* ffw      = (const float*)d_in[4];
    const float* ffb      = (const float*)d_in[5];
    const float* lbias    = (const float*)d_in[6];

    float* out_scores = (float*)d_out;
    float* out_mask   = out_scores + (size_t)B_ * L_ * T_ * T_;  // 33554432

    char* ws = (char*)d_ws;
    float*          stats  = (float*)ws;                              // 16 KiB
    unsigned short* feats  = (unsigned short*)(ws + 16384);           // 6 MiB
    unsigned short* wbf    = (unsigned short*)(ws + 16384 + 6291456); // 6 MiB
    unsigned short* startp = (unsigned short*)(ws + 12599296);        // 16 MiB
    unsigned short* endp   = (unsigned short*)(ws + 29376512);        // 16 MiB

    hipMemsetAsync(ws, 0, 16384, stream);
    k_stats<<<256, 256, 0, stream>>>(features, mask, stats);
    k_normcast<<<6144, 256, 0, stream>>>((const float4*)features, (const float4*)ffw,
                                         mask, stats, gamma, beta, feats, wbf);
    k_ffn<<<1024, 512, 0, stream>>>(feats, wbf, ffb, startp, endp);
    k_biaffine<<<2048, 256, 0, stream>>>(startp, endp, mask, lbias, out_scores, out_mask);
}

// Round 6
// 339.489 us; speedup vs baseline: 1.2100x; 1.0348x over previous
//
#include <hip/hip_runtime.h>

#define B_    8
#define T_    512
#define D_    768
#define L_    16
#define DL_   128
#define NO_   4096   // L_*DL_*2
#define M_    4096   // B_*T_
#define BN_EPS 1e-5f

typedef __attribute__((ext_vector_type(8))) short short8;
typedef __attribute__((ext_vector_type(4))) float f32x4;
typedef __attribute__((ext_vector_type(2))) float f32x2;

__device__ inline unsigned short f2bf(float x) {
    unsigned int u = __float_as_uint(x);
    unsigned int r = (u + 0x7fffu + ((u >> 16) & 1u)) >> 16;
    return (unsigned short)r;
}

// async global -> LDS, 16 bytes per lane (dest = uniform base + lane*16)
__device__ __forceinline__ void gload_lds16(const unsigned short* g, unsigned short* l) {
    __builtin_amdgcn_global_load_lds(
        (const __attribute__((address_space(1))) unsigned int*)g,
        (__attribute__((address_space(3))) unsigned int*)l, 16, 0, 0);
}

// ---------------- Kernel 1: masked per-channel sum / sumsq / count ----------
__global__ void k_stats(const float* __restrict__ f, const int* __restrict__ mask,
                        float* __restrict__ stats) {
    int tid = threadIdx.x;
    int t0  = blockIdx.x * 16;
    float s0 = 0.f, s1 = 0.f, s2 = 0.f, q0 = 0.f, q1 = 0.f, q2 = 0.f;
    for (int tt = 0; tt < 16; ++tt) {
        int t = t0 + tt;
        float m = mask[t] ? 1.f : 0.f;
        const float* row = f + (size_t)t * D_;
        float x0 = row[tid];
        float x1 = row[tid + 256];
        float x2 = row[tid + 512];
        s0 += x0 * m; q0 += x0 * x0 * m;
        s1 += x1 * m; q1 += x1 * x1 * m;
        s2 += x2 * m; q2 += x2 * x2 * m;
    }
    atomicAdd(&stats[tid      ], s0);
    atomicAdd(&stats[tid + 256], s1);
    atomicAdd(&stats[tid + 512], s2);
    atomicAdd(&stats[768 + tid      ], q0);
    atomicAdd(&stats[768 + tid + 256], q1);
    atomicAdd(&stats[768 + tid + 512], q2);
    if (tid == 0) {
        int c = 0;
        for (int tt = 0; tt < 16; ++tt) c += (mask[t0 + tt] ? 1 : 0);
        atomicAdd(&stats[1536], (float)c);
    }
}

// ---------------- Kernel 2: normalize+mask+cast feats, cast ff_w ------------
// (finalize folded in; bit-identical to two-kernel version)
__global__ void k_normcast(const float4* __restrict__ f4, const float4* __restrict__ w4,
                           const int* __restrict__ mask, const float* __restrict__ stats,
                           const float* __restrict__ gamma, const float* __restrict__ beta,
                           unsigned short* __restrict__ featp, unsigned short* __restrict__ wp) {
    int i = blockIdx.x * 256 + threadIdx.x;
    if (i < M_ * D_ / 4) {
        int d4 = i % (D_ / 4);
        int t  = i / (D_ / 4);
        float m = mask[t] ? 1.f : 0.f;
        float4 v = f4[i];
        int d = d4 * 4;
        float denom = fmaxf(stats[1536], 1.f);
        float sc[4], sh[4];
#pragma unroll
        for (int c = 0; c < 4; ++c) {
            float mean = stats[d + c] / denom;
            float var  = fmaxf(stats[768 + d + c] / denom - mean * mean, 0.f);
            float s    = gamma[d + c] * rsqrtf(var + BN_EPS);
            sc[c] = s;
            sh[c] = beta[d + c] - mean * s;
        }
        float r0 = (v.x * sc[0] + sh[0]) * m;
        float r1 = (v.y * sc[1] + sh[1]) * m;
        float r2 = (v.z * sc[2] + sh[2]) * m;
        float r3 = (v.w * sc[3] + sh[3]) * m;
        ushort4 o;
        o.x = f2bf(r0); o.y = f2bf(r1); o.z = f2bf(r2); o.w = f2bf(r3);
        ((ushort4*)featp)[i] = o;
    } else {
        int j = i - M_ * D_ / 4;
        float4 v = w4[j];
        ushort4 o;
        o.x = f2bf(v.x); o.y = f2bf(v.y); o.z = f2bf(v.z); o.w = f2bf(v.w);
        ((ushort4*)wp)[j] = o;
    }
}

// ---------------- Kernel 3: FFN GEMM (h = relu(feats @ W^T + b)) ------------
// Widened counted-vmcnt pipeline: 256x128 tile, BK=64, 3 LDS slots
// (A 32KB + B 16KB per slot = 144 KB), 8 waves (4Mx2N, wave-tile 64x64,
// acc[4][4]). Per phase: 32 MFMA vs 6 gloads (2x the MFMA per barrier of the
// round-5 kernel). Slot safety: write slot (t+2)%3 == slot read at phase
// t-1, whose ds_reads completed before this phase's barrier (WAR-safe);
// RAW gated by vmcnt(6) (= one phase's 6 loads left in flight).
// K-slice accumulation order unchanged -> bit-identical output.
// Coalesced epilogue via LDS bounce (round-5 structure, 256 rows).
__launch_bounds__(512, 2)
__global__ void k_ffn(const unsigned short* __restrict__ A, const unsigned short* __restrict__ W,
                      const float* __restrict__ bias,
                      unsigned short* __restrict__ startp, unsigned short* __restrict__ endp) {
    __shared__ alignas(16) unsigned short LA[3][16384];   // 3 x 256x64
    __shared__ alignas(16) unsigned short LB[3][8192];    // 3 x 128x64
    int h   = blockIdx.x;                 // 512 blocks
    int xcd = h & 7, q = h >> 3;          // q in [0,64)
    int bm  = xcd * 2 + (q >> 5);         // 2 bm panels (256 rows) per XCD
    int bn  = q & 31;
    int tid  = threadIdx.x;
    int wave = tid >> 6, lane = tid & 63;
    int wm = wave >> 1, wn = wave & 1;
    int lr = lane & 15, quad = lane >> 4;
    int srow = lane >> 3;
    int sg   = (lane & 7) ^ srow;
    const unsigned short* asrc[4];
    const unsigned short* bsrc[2];
#pragma unroll
    for (int p = 0; p < 4; ++p) {
        int c = wave * 4 + p;             // A chunk 0..31, rows c*8..c*8+7
        asrc[p] = A + (size_t)(bm * 256 + c * 8 + srow) * D_ + sg * 8;
    }
#pragma unroll
    for (int p = 0; p < 2; ++p) {
        int c = wave * 2 + p;             // B chunk 0..15
        bsrc[p] = W + (size_t)(bn * 128 + c * 8 + srow) * D_ + sg * 8;
    }
    int aoff[4][2], boff[4][2];
#pragma unroll
    for (int i = 0; i < 4; ++i)
#pragma unroll
        for (int kk = 0; kk < 2; ++kk) {
            int row = wm * 64 + i * 16 + lr;
            aoff[i][kk] = row * 64 + ((kk * 4 + quad) ^ (row & 7)) * 8;
        }
#pragma unroll
    for (int j = 0; j < 4; ++j)
#pragma unroll
        for (int kk = 0; kk < 2; ++kk) {
            int row = wn * 64 + j * 16 + lr;
            boff[j][kk] = row * 64 + ((kk * 4 + quad) ^ (row & 7)) * 8;
        }
    f32x4 acc[4][4] = {};
    // prologue: stage tiles 0,1 into slots 0,1 (6 gloads per wave per tile)
#pragma unroll
    for (int t = 0; t < 2; ++t) {
#pragma unroll
        for (int p = 0; p < 4; ++p)
            gload_lds16(asrc[p] + t * 64, &LA[t][(wave * 4 + p) * 512]);
#pragma unroll
        for (int p = 0; p < 2; ++p)
            gload_lds16(bsrc[p] + t * 64, &LB[t][(wave * 2 + p) * 512]);
    }
    // 12 K-tiles of 64 (K = 768)
#pragma unroll
    for (int t = 0; t < 12; ++t) {
        if (t == 11) asm volatile("s_waitcnt vmcnt(0)\ns_barrier" ::: "memory");
        else         asm volatile("s_waitcnt vmcnt(6)\ns_barrier" ::: "memory");
        const unsigned short* la = LA[t % 3];
        const unsigned short* lb = LB[t % 3];
        short8 af[4][2], bf[4][2];
#pragma unroll
        for (int i = 0; i < 4; ++i)
#pragma unroll
            for (int kk = 0; kk < 2; ++kk)
                af[i][kk] = *(const short8*)&la[aoff[i][kk]];
#pragma unroll
        for (int j = 0; j < 4; ++j)
#pragma unroll
            for (int kk = 0; kk < 2; ++kk)
                bf[j][kk] = *(const short8*)&lb[boff[j][kk]];
        if (t < 10) {
            int ss = (t + 2) % 3;
            int ko = (t + 2) * 64;
#pragma unroll
            for (int p = 0; p < 4; ++p)
                gload_lds16(asrc[p] + ko, &LA[ss][(wave * 4 + p) * 512]);
#pragma unroll
            for (int p = 0; p < 2; ++p)
                gload_lds16(bsrc[p] + ko, &LB[ss][(wave * 2 + p) * 512]);
        }
        __builtin_amdgcn_s_setprio(1);
#pragma unroll
        for (int kk = 0; kk < 2; ++kk)
#pragma unroll
            for (int i = 0; i < 4; ++i)
#pragma unroll
                for (int j = 0; j < 4; ++j)
                    acc[i][j] = __builtin_amdgcn_mfma_f32_16x16x32_bf16(af[i][kk], bf[j][kk], acc[i][j], 0, 0, 0);
        __builtin_amdgcn_s_setprio(0);
    }
    // ---- epilogue: LDS bounce, de-interleaved, then 128B-run stores ----
    __syncthreads();                       // all frag reads done; reuse LA
    unsigned short* C16 = &LA[0][0];       // 256 rows x 136 shorts = 69.6 KB
#pragma unroll
    for (int i = 0; i < 4; ++i) {
#pragma unroll
        for (int j = 0; j < 4; ++j) {
            int col_local = wn * 64 + j * 16 + lr;           // 0..127
            float bv = bias[bn * 128 + col_local];
            int a   = col_local & 1;                          // start/end
            int ddp = col_local >> 1;                         // 0..63
#pragma unroll
            for (int r = 0; r < 4; ++r) {
                int row = wm * 64 + i * 16 + quad * 4 + r;    // 0..255
                float v = fmaxf(acc[i][j][r] + bv, 0.f);
                C16[row * 136 + a * 64 + ddp] = f2bf(v);
            }
        }
    }
    __syncthreads();
    int l      = bn >> 1;
    int ddbase = (bn & 1) * 64;
#pragma unroll
    for (int it = 0; it < 8; ++it) {
        int flat  = it * 512 + tid;        // 0..4095
        int piece = flat & 7;              // which 16B of the 128B run
        int run   = flat >> 3;             // 0..511 = (row, a)
        int a     = run & 1;
        int row   = run >> 1;              // 0..255
        int tg    = bm * 256 + row;        // global token
        int bb    = tg >> 9, tt = tg & 511;
        uint4 v = *(const uint4*)&C16[row * 136 + a * 64 + piece * 8];
        unsigned short* dst = a ? endp : startp;
        size_t off = ((size_t)(bb * 16 + l) * 512 + tt) * 128 + ddbase + piece * 8;
        *(uint4*)&dst[off] = v;
    }
}

// ---------------- Kernel 4: biaffine scores + spans_mask (fused) ------------
// Compute loop unchanged (passed 3x). Readout widened: f32x4 per lane
// (32 lanes cover one 512B row-run; wave writes 2 rows per iteration) ->
// half the NT store instructions, 1KB runs.
__launch_bounds__(256)
__global__ void k_biaffine(const unsigned short* __restrict__ startp,
                           const unsigned short* __restrict__ endp,
                           const int* __restrict__ mask,
                           const float* __restrict__ lbias,
                           float* __restrict__ out_scores, float* __restrict__ out_mask) {
    __shared__ alignas(16) float smemf[64 * 132];
    unsigned short* As = (unsigned short*)smemf;          // 128*64 shorts
    unsigned short* Bs = As + 128 * 64;
    float* Cs = smemf;
    int hgrid = blockIdx.x;
    int xcd = hgrid & 7, q = hgrid >> 3;  // q in [0,256)
    int bl  = xcd * 16 + (q >> 4);        // 16 bl planes per XCD
    int inner = q & 15;
    int bm = inner & 3, bn = inner >> 2;
    int b  = bl >> 4;
    int tid = threadIdx.x;
    const unsigned short* A  = startp + (size_t)bl * 512 * 128;
    const unsigned short* Bp = endp   + (size_t)bl * 512 * 128;
    int wave = tid >> 6, lane = tid & 63;
    int wm = wave >> 1, wn = wave & 1;
    int lr = lane & 15, quad = lane >> 4;
    f32x4 acc[4][4] = {};
    int srow = lane >> 3;
    for (int half = 0; half < 2; ++half) {
#pragma unroll
        for (int p = 0; p < 4; ++p) {
            int c   = wave * 4 + p;
            int row = c * 8 + srow;
            int gl  = (lane & 7) ^ (row & 7);
            gload_lds16(A  + (size_t)(bm * 128 + row) * DL_ + half * 64 + gl * 8, &As[c * 512]);
            gload_lds16(Bp + (size_t)(bn * 128 + row) * DL_ + half * 64 + gl * 8, &Bs[c * 512]);
        }
        __syncthreads();
#pragma unroll
        for (int kk = 0; kk < 2; ++kk) {
            short8 a[4], bb[4];
#pragma unroll
            for (int i = 0; i < 4; ++i) {
                int row = wm * 64 + i * 16 + lr;
                int gp  = (kk * 4 + quad) ^ (row & 7);
                a[i] = *(const short8*)&As[row * 64 + gp * 8];
            }
#pragma unroll
            for (int j = 0; j < 4; ++j) {
                int row = wn * 64 + j * 16 + lr;
                int gp  = (kk * 4 + quad) ^ (row & 7);
                bb[j] = *(const short8*)&Bs[row * 64 + gp * 8];
            }
#pragma unroll
            for (int i = 0; i < 4; ++i)
#pragma unroll
                for (int j = 0; j < 4; ++j)
                    acc[i][j] = __builtin_amdgcn_mfma_f32_16x16x32_bf16(a[i], bb[j], acc[i][j], 0, 0, 0);
        }
        __syncthreads();
    }
    float lb = lbias[bl & 15];
    float* obase = out_scores + (size_t)bl * 512 * 512;
    float* mbase = out_mask   + (size_t)bl * 512 * 512;
    // lane -> (row-pair half rp, 4 consecutive e columns)
    int rp   = lane >> 5;                  // 0/1
    int colq = (lane & 31) * 4;            // 0..124
    int e0   = bn * 128 + colq;
    float me[4];
#pragma unroll
    for (int c = 0; c < 4; ++c) me[c] = mask[b * 512 + e0 + c] ? 1.f : 0.f;
    for (int hh = 0; hh < 2; ++hh) {
        if (wm == hh) {
#pragma unroll
            for (int i = 0; i < 4; ++i)
#pragma unroll
                for (int j = 0; j < 4; ++j)
#pragma unroll
                    for (int r = 0; r < 4; ++r)
                        Cs[(i * 16 + quad * 4 + r) * 132 + wn * 64 + j * 16 + lr] = acc[i][j][r];
        }
        __syncthreads();
#pragma unroll
        for (int rr = 0; rr < 8; ++rr) {
            int rloc = wave * 16 + rr * 2 + rp;
            int s = bm * 128 + hh * 64 + rloc;
            f32x4 v = *(const f32x4*)&Cs[rloc * 132 + colq];
            v[0] += lb; v[1] += lb; v[2] += lb; v[3] += lb;
            float ms = mask[b * 512 + s] ? 1.f : 0.f;
            f32x4 mk;
#pragma unroll
            for (int c = 0; c < 4; ++c) mk[c] = (s <= e0 + c) ? ms * me[c] : 0.f;
            size_t off = (size_t)s * 512 + e0;
            __builtin_nontemporal_store(v,  (f32x4*)&obase[off]);
            __builtin_nontemporal_store(mk, (f32x4*)&mbase[off]);
        }
        __syncthreads();
    }
}

extern "C" void kernel_launch(void* const* d_in, const int* in_sizes, int n_in,
                              void* d_out, int out_size, void* d_ws, size_t ws_size,
                              hipStream_t stream) {
    const float* features = (const float*)d_in[0];
    const int*   mask     = (const int*)d_in[1];
    const float* gamma    = (const float*)d_in[2];
    const float* beta     = (const float*)d_in[3];
    const float* ffw      = (const float*)d_in[4];
    const float* ffb      = (const float*)d_in[5];
    const float* lbias    = (const float*)d_in[6];

    float* out_scores = (float*)d_out;
    float* out_mask   = out_scores + (size_t)B_ * L_ * T_ * T_;  // 33554432

    char* ws = (char*)d_ws;
    float*          stats  = (float*)ws;                              // 16 KiB
    unsigned short* feats  = (unsigned short*)(ws + 16384);           // 6 MiB
    unsigned short* wbf    = (unsigned short*)(ws + 16384 + 6291456); // 6 MiB
    unsigned short* startp = (unsigned short*)(ws + 12599296);        // 16 MiB
    unsigned short* endp   = (unsigned short*)(ws + 29376512);        // 16 MiB

    hipMemsetAsync(ws, 0, 16384, stream);
    k_stats<<<256, 256, 0, stream>>>(features, mask, stats);
    k_normcast<<<6144, 256, 0, stream>>>((const float4*)features, (const float4*)ffw,
                                         mask, stats, gamma, beta, feats, wbf);
    k_ffn<<<512, 512, 0, stream>>>(feats, wbf, ffb, startp, endp);
    k_biaffine<<<2048, 256, 0, stream>>>(startp, endp, mask, lbias, out_scores, out_mask);
}

// Round 9
// 337.632 us; speedup vs baseline: 1.2167x; 1.0055x over previous
//
#include <hip/hip_runtime.h>

#define B_    8
#define T_    512
#define D_    768
#define L_    16
#define DL_   128
#define NO_   4096   // L_*DL_*2
#define M_    4096   // B_*T_
#define BN_EPS 1e-5f

typedef __attribute__((ext_vector_type(8))) short short8;
typedef __attribute__((ext_vector_type(4))) float f32x4;
typedef __attribute__((ext_vector_type(2))) float f32x2;

__device__ inline unsigned short f2bf(float x) {
    unsigned int u = __float_as_uint(x);
    unsigned int r = (u + 0x7fffu + ((u >> 16) & 1u)) >> 16;
    return (unsigned short)r;
}

// async global -> LDS, 16 bytes per lane (dest = uniform base + lane*16)
__device__ __forceinline__ void gload_lds16(const unsigned short* g, unsigned short* l) {
    __builtin_amdgcn_global_load_lds(
        (const __attribute__((address_space(1))) unsigned int*)g,
        (__attribute__((address_space(3))) unsigned int*)l, 16, 0, 0);
}

// ---------------- Kernel 1: masked per-channel sum / sumsq / count ----------
__global__ void k_stats(const float* __restrict__ f, const int* __restrict__ mask,
                        float* __restrict__ stats) {
    int tid = threadIdx.x;
    int t0  = blockIdx.x * 16;
    float s0 = 0.f, s1 = 0.f, s2 = 0.f, q0 = 0.f, q1 = 0.f, q2 = 0.f;
    for (int tt = 0; tt < 16; ++tt) {
        int t = t0 + tt;
        float m = mask[t] ? 1.f : 0.f;
        const float* row = f + (size_t)t * D_;
        float x0 = row[tid];
        float x1 = row[tid + 256];
        float x2 = row[tid + 512];
        s0 += x0 * m; q0 += x0 * x0 * m;
        s1 += x1 * m; q1 += x1 * x1 * m;
        s2 += x2 * m; q2 += x2 * x2 * m;
    }
    atomicAdd(&stats[tid      ], s0);
    atomicAdd(&stats[tid + 256], s1);
    atomicAdd(&stats[tid + 512], s2);
    atomicAdd(&stats[768 + tid      ], q0);
    atomicAdd(&stats[768 + tid + 256], q1);
    atomicAdd(&stats[768 + tid + 512], q2);
    if (tid == 0) {
        int c = 0;
        for (int tt = 0; tt < 16; ++tt) c += (mask[t0 + tt] ? 1 : 0);
        atomicAdd(&stats[1536], (float)c);
    }
}

// ---------------- Kernel 2: normalize+mask+cast feats, cast ff_w ------------
// (finalize folded in; bit-identical to two-kernel version)
__global__ void k_normcast(const float4* __restrict__ f4, const float4* __restrict__ w4,
                           const int* __restrict__ mask, const float* __restrict__ stats,
                           const float* __restrict__ gamma, const float* __restrict__ beta,
                           unsigned short* __restrict__ featp, unsigned short* __restrict__ wp) {
    int i = blockIdx.x * 256 + threadIdx.x;
    if (i < M_ * D_ / 4) {
        int d4 = i % (D_ / 4);
        int t  = i / (D_ / 4);
        float m = mask[t] ? 1.f : 0.f;
        float4 v = f4[i];
        int d = d4 * 4;
        float denom = fmaxf(stats[1536], 1.f);
        float sc[4], sh[4];
#pragma unroll
        for (int c = 0; c < 4; ++c) {
            float mean = stats[d + c] / denom;
            float var  = fmaxf(stats[768 + d + c] / denom - mean * mean, 0.f);
            float s    = gamma[d + c] * rsqrtf(var + BN_EPS);
            sc[c] = s;
            sh[c] = beta[d + c] - mean * s;
        }
        float r0 = (v.x * sc[0] + sh[0]) * m;
        float r1 = (v.y * sc[1] + sh[1]) * m;
        float r2 = (v.z * sc[2] + sh[2]) * m;
        float r3 = (v.w * sc[3] + sh[3]) * m;
        ushort4 o;
        o.x = f2bf(r0); o.y = f2bf(r1); o.z = f2bf(r2); o.w = f2bf(r3);
        ((ushort4*)featp)[i] = o;
    } else {
        int j = i - M_ * D_ / 4;
        float4 v = w4[j];
        ushort4 o;
        o.x = f2bf(v.x); o.y = f2bf(v.y); o.z = f2bf(v.z); o.w = f2bf(v.w);
        ((ushort4*)wp)[j] = o;
    }
}

// ---------------- Kernel 3: FFN GEMM (h = relu(feats @ W^T + b)) ------------
// Widened counted-vmcnt pipeline: 256x128 tile, BK=64, 3 LDS slots
// (A 32KB + B 16KB per slot = 144 KB), 8 waves (4Mx2N, wave-tile 64x64,
// acc[4][4]). Per phase: 32 MFMA vs 6 gloads. Slot safety: write slot
// (t+2)%3 == slot read at phase t-1, whose ds_reads completed before this
// phase's barrier (WAR-safe); RAW gated by vmcnt(6).
// K-slice accumulation order unchanged -> bit-identical output.
// Coalesced epilogue via LDS bounce (round-5 structure, 256 rows).
__launch_bounds__(512, 2)
__global__ void k_ffn(const unsigned short* __restrict__ A, const unsigned short* __restrict__ W,
                      const float* __restrict__ bias,
                      unsigned short* __restrict__ startp, unsigned short* __restrict__ endp) {
    __shared__ alignas(16) unsigned short LA[3][16384];   // 3 x 256x64
    __shared__ alignas(16) unsigned short LB[3][8192];    // 3 x 128x64
    int h   = blockIdx.x;                 // 512 blocks
    int xcd = h & 7, q = h >> 3;          // q in [0,64)
    int bm  = xcd * 2 + (q >> 5);         // 2 bm panels (256 rows) per XCD
    int bn  = q & 31;
    int tid  = threadIdx.x;
    int wave = tid >> 6, lane = tid & 63;
    int wm = wave >> 1, wn = wave & 1;
    int lr = lane & 15, quad = lane >> 4;
    int srow = lane >> 3;
    int sg   = (lane & 7) ^ srow;
    const unsigned short* asrc[4];
    const unsigned short* bsrc[2];
#pragma unroll
    for (int p = 0; p < 4; ++p) {
        int c = wave * 4 + p;             // A chunk 0..31, rows c*8..c*8+7
        asrc[p] = A + (size_t)(bm * 256 + c * 8 + srow) * D_ + sg * 8;
    }
#pragma unroll
    for (int p = 0; p < 2; ++p) {
        int c = wave * 2 + p;             // B chunk 0..15
        bsrc[p] = W + (size_t)(bn * 128 + c * 8 + srow) * D_ + sg * 8;
    }
    int aoff[4][2], boff[4][2];
#pragma unroll
    for (int i = 0; i < 4; ++i)
#pragma unroll
        for (int kk = 0; kk < 2; ++kk) {
            int row = wm * 64 + i * 16 + lr;
            aoff[i][kk] = row * 64 + ((kk * 4 + quad) ^ (row & 7)) * 8;
        }
#pragma unroll
    for (int j = 0; j < 4; ++j)
#pragma unroll
        for (int kk = 0; kk < 2; ++kk) {
            int row = wn * 64 + j * 16 + lr;
            boff[j][kk] = row * 64 + ((kk * 4 + quad) ^ (row & 7)) * 8;
        }
    f32x4 acc[4][4] = {};
    // prologue: stage tiles 0,1 into slots 0,1 (6 gloads per wave per tile)
#pragma unroll
    for (int t = 0; t < 2; ++t) {
#pragma unroll
        for (int p = 0; p < 4; ++p)
            gload_lds16(asrc[p] + t * 64, &LA[t][(wave * 4 + p) * 512]);
#pragma unroll
        for (int p = 0; p < 2; ++p)
            gload_lds16(bsrc[p] + t * 64, &LB[t][(wave * 2 + p) * 512]);
    }
    // 12 K-tiles of 64 (K = 768)
#pragma unroll
    for (int t = 0; t < 12; ++t) {
        if (t == 11) asm volatile("s_waitcnt vmcnt(0)\ns_barrier" ::: "memory");
        else         asm volatile("s_waitcnt vmcnt(6)\ns_barrier" ::: "memory");
        const unsigned short* la = LA[t % 3];
        const unsigned short* lb = LB[t % 3];
        short8 af[4][2], bf[4][2];
#pragma unroll
        for (int i = 0; i < 4; ++i)
#pragma unroll
            for (int kk = 0; kk < 2; ++kk)
                af[i][kk] = *(const short8*)&la[aoff[i][kk]];
#pragma unroll
        for (int j = 0; j < 4; ++j)
#pragma unroll
            for (int kk = 0; kk < 2; ++kk)
                bf[j][kk] = *(const short8*)&lb[boff[j][kk]];
        if (t < 10) {
            int ss = (t + 2) % 3;
            int ko = (t + 2) * 64;
#pragma unroll
            for (int p = 0; p < 4; ++p)
                gload_lds16(asrc[p] + ko, &LA[ss][(wave * 4 + p) * 512]);
#pragma unroll
            for (int p = 0; p < 2; ++p)
                gload_lds16(bsrc[p] + ko, &LB[ss][(wave * 2 + p) * 512]);
        }
        __builtin_amdgcn_s_setprio(1);
#pragma unroll
        for (int kk = 0; kk < 2; ++kk)
#pragma unroll
            for (int i = 0; i < 4; ++i)
#pragma unroll
                for (int j = 0; j < 4; ++j)
                    acc[i][j] = __builtin_amdgcn_mfma_f32_16x16x32_bf16(af[i][kk], bf[j][kk], acc[i][j], 0, 0, 0);
        __builtin_amdgcn_s_setprio(0);
    }
    // ---- epilogue: LDS bounce, de-interleaved, then 128B-run stores ----
    __syncthreads();                       // all frag reads done; reuse LA
    unsigned short* C16 = &LA[0][0];       // 256 rows x 136 shorts = 69.6 KB
#pragma unroll
    for (int i = 0; i < 4; ++i) {
#pragma unroll
        for (int j = 0; j < 4; ++j) {
            int col_local = wn * 64 + j * 16 + lr;           // 0..127
            float bv = bias[bn * 128 + col_local];
            int a   = col_local & 1;                          // start/end
            int ddp = col_local >> 1;                         // 0..63
#pragma unroll
            for (int r = 0; r < 4; ++r) {
                int row = wm * 64 + i * 16 + quad * 4 + r;    // 0..255
                float v = fmaxf(acc[i][j][r] + bv, 0.f);
                C16[row * 136 + a * 64 + ddp] = f2bf(v);
            }
        }
    }
    __syncthreads();
    int l      = bn >> 1;
    int ddbase = (bn & 1) * 64;
#pragma unroll
    for (int it = 0; it < 8; ++it) {
        int flat  = it * 512 + tid;        // 0..4095
        int piece = flat & 7;              // which 16B of the 128B run
        int run   = flat >> 3;             // 0..511 = (row, a)
        int a     = run & 1;
        int row   = run >> 1;              // 0..255
        int tg    = bm * 256 + row;        // global token
        int bb    = tg >> 9, tt = tg & 511;
        uint4 v = *(const uint4*)&C16[row * 136 + a * 64 + piece * 8];
        unsigned short* dst = a ? endp : startp;
        size_t off = ((size_t)(bb * 16 + l) * 512 + tt) * 128 + ddbase + piece * 8;
        *(uint4*)&dst[off] = v;
    }
}

// ---------------- Kernel 4: biaffine scores + spans_mask (fused) ------------
// Compute loop unchanged (passed 3x). Readout: f32x4 per lane
// (32 lanes cover one 512B row-run; wave writes 2 rows per iteration).
__launch_bounds__(256)
__global__ void k_biaffine(const unsigned short* __restrict__ startp,
                           const unsigned short* __restrict__ endp,
                           const int* __restrict__ mask,
                           const float* __restrict__ lbias,
                           float* __restrict__ out_scores, float* __restrict__ out_mask) {
    __shared__ alignas(16) float smemf[64 * 132];
    unsigned short* As = (unsigned short*)smemf;          // 128*64 shorts
    unsigned short* Bs = As + 128 * 64;
    float* Cs = smemf;
    int hgrid = blockIdx.x;
    int xcd = hgrid & 7, q = hgrid >> 3;  // q in [0,256)
    int bl  = xcd * 16 + (q >> 4);        // 16 bl planes per XCD
    int inner = q & 15;
    int bm = inner & 3, bn = inner >> 2;
    int b  = bl >> 4;
    int tid = threadIdx.x;
    const unsigned short* A  = startp + (size_t)bl * 512 * 128;
    const unsigned short* Bp = endp   + (size_t)bl * 512 * 128;
    int wave = tid >> 6, lane = tid & 63;
    int wm = wave >> 1, wn = wave & 1;
    int lr = lane & 15, quad = lane >> 4;
    f32x4 acc[4][4] = {};
    int srow = lane >> 3;
    for (int half = 0; half < 2; ++half) {
#pragma unroll
        for (int p = 0; p < 4; ++p) {
            int c   = wave * 4 + p;
            int row = c * 8 + srow;
            int gl  = (lane & 7) ^ (row & 7);
            gload_lds16(A  + (size_t)(bm * 128 + row) * DL_ + half * 64 + gl * 8, &As[c * 512]);
            gload_lds16(Bp + (size_t)(bn * 128 + row) * DL_ + half * 64 + gl * 8, &Bs[c * 512]);
        }
        __syncthreads();
#pragma unroll
        for (int kk = 0; kk < 2; ++kk) {
            short8 a[4], bb[4];
#pragma unroll
            for (int i = 0; i < 4; ++i) {
                int row = wm * 64 + i * 16 + lr;
                int gp  = (kk * 4 + quad) ^ (row & 7);
                a[i] = *(const short8*)&As[row * 64 + gp * 8];
            }
#pragma unroll
            for (int j = 0; j < 4; ++j) {
                int row = wn * 64 + j * 16 + lr;
                int gp  = (kk * 4 + quad) ^ (row & 7);
                bb[j] = *(const short8*)&Bs[row * 64 + gp * 8];
            }
#pragma unroll
            for (int i = 0; i < 4; ++i)
#pragma unroll
                for (int j = 0; j < 4; ++j)
                    acc[i][j] = __builtin_amdgcn_mfma_f32_16x16x32_bf16(a[i], bb[j], acc[i][j], 0, 0, 0);
        }
        __syncthreads();
    }
    float lb = lbias[bl & 15];
    float* obase = out_scores + (size_t)bl * 512 * 512;
    float* mbase = out_mask   + (size_t)bl * 512 * 512;
    // lane -> (row-pair half rp, 4 consecutive e columns)
    int rp   = lane >> 5;                  // 0/1
    int colq = (lane & 31) * 4;            // 0..124
    int e0   = bn * 128 + colq;
    float me[4];
#pragma unroll
    for (int c = 0; c < 4; ++c) me[c] = mask[b * 512 + e0 + c] ? 1.f : 0.f;
    for (int hh = 0; hh < 2; ++hh) {
        if (wm == hh) {
#pragma unroll
            for (int i = 0; i < 4; ++i)
#pragma unroll
                for (int j = 0; j < 4; ++j)
#pragma unroll
                    for (int r = 0; r < 4; ++r)
                        Cs[(i * 16 + quad * 4 + r) * 132 + wn * 64 + j * 16 + lr] = acc[i][j][r];
        }
        __syncthreads();
#pragma unroll
        for (int rr = 0; rr < 8; ++rr) {
            int rloc = wave * 16 + rr * 2 + rp;
            int s = bm * 128 + hh * 64 + rloc;
            f32x4 v = *(const f32x4*)&Cs[rloc * 132 + colq];
            v[0] += lb; v[1] += lb; v[2] += lb; v[3] += lb;
            float ms = mask[b * 512 + s] ? 1.f : 0.f;
            f32x4 mk;
#pragma unroll
            for (int c = 0; c < 4; ++c) mk[c] = (s <= e0 + c) ? ms * me[c] : 0.f;
            size_t off = (size_t)s * 512 + e0;
            __builtin_nontemporal_store(v,  (f32x4*)&obase[off]);
            __builtin_nontemporal_store(mk, (f32x4*)&mbase[off]);
        }
        __syncthreads();
    }
}

extern "C" void kernel_launch(void* const* d_in, const int* in_sizes, int n_in,
                              void* d_out, int out_size, void* d_ws, size_t ws_size,
                              hipStream_t stream) {
    const float* features = (const float*)d_in[0];
    const int*   mask     = (const int*)d_in[1];
    const float* gamma    = (const float*)d_in[2];
    const float* beta     = (const float*)d_in[3];
    const float* ffw      = (const float*)d_in[4];
    const float* ffb      = (const float*)d_in[5];
    const float* lbias    = (const float*)d_in[6];

    float* out_scores = (float*)d_out;
    float* out_mask   = out_scores + (size_t)B_ * L_ * T_ * T_;  // 33554432

    char* ws = (char*)d_ws;
    float*          stats  = (float*)ws;                              // 16 KiB
    unsigned short* feats  = (unsigned short*)(ws + 16384);           // 6 MiB
    unsigned short* wbf    = (unsigned short*)(ws + 16384 + 6291456); // 6 MiB
    unsigned short* startp = (unsigned short*)(ws + 12599296);        // 16 MiB
    unsigned short* endp   = (unsigned short*)(ws + 29376512);        // 16 MiB

    hipMemsetAsync(ws, 0, 16384, stream);
    k_stats<<<256, 256, 0, stream>>>(features, mask, stats);
    k_normcast<<<6144, 256, 0, stream>>>((const float4*)features, (const float4*)ffw,
                                         mask, stats, gamma, beta, feats, wbf);
    k_ffn<<<512, 512, 0, stream>>>(feats, wbf, ffb, startp, endp);
    k_biaffine<<<2048, 256, 0, stream>>>(startp, endp, mask, lbias, out_scores, out_mask);
}